// Round 1
// baseline (36835.251 us; speedup 1.0000x reference)
//
#include <hip/hip_runtime.h>
#include <math.h>

#define NTOK 201
#define EDIM 128
#define LDX  129        // padded x stride (2-way LDS aliasing = free)
#define NHEAD 4
#define HD   32
#define NLAYER 6
#define NEXPERT 5
#define FFD  256
#define NCAT 53
#define NNUM 47
#define NENG 100
#define NEMBED 1352
#define SEQL 51
#define NBATCH 512
#define LN_EPS 1e-5f
#define KVP  32         // K/V row stride: 128B rows, 16B-aligned for float4 reads

struct Params {
  const int*   x_cat;
  const float* x_num;
  const float* x_eng;
  const float* emb;
  const float* emb_bias;
  const float* emb_eng;
  const float* emb_bias_eng;
  const float* ln0w; const float* ln0b;
  const float* ln1w; const float* ln1b;
  const float* Wqkv; const float* bqkv;
  const float* Wo;   const float* bo;
  const float* ln2w; const float* ln2b;
  const float* Wg;   const float* bg;
  const float* W1;   const float* b1;
  const float* W2;   const float* b2;
  float* out;
};

// mean / rstd per token row (thread-per-token)
__device__ __forceinline__ void ln_stats(const float* xs, float* s_m, float* s_r, int tid) {
  if (tid < NTOK) {
    const float* row = xs + tid * LDX;
    float s0 = 0.f, s1 = 0.f, s2 = 0.f, s3 = 0.f;
    for (int e = 0; e < EDIM; e += 4) {
      s0 += row[e]; s1 += row[e + 1]; s2 += row[e + 2]; s3 += row[e + 3];
    }
    float m = (s0 + s1 + s2 + s3) * (1.0f / EDIM);
    float v0 = 0.f, v1 = 0.f, v2 = 0.f, v3 = 0.f;
    for (int e = 0; e < EDIM; e += 4) {
      float d0 = row[e] - m, d1 = row[e + 1] - m, d2 = row[e + 2] - m, d3 = row[e + 3] - m;
      v0 += d0 * d0; v1 += d1 * d1; v2 += d2 * d2; v3 += d3 * d3;
    }
    float v = (v0 + v1 + v2 + v3) * (1.0f / EDIM);
    s_m[tid] = m;
    s_r[tid] = 1.0f / sqrtf(v + LN_EPS);
  }
}

__global__ __launch_bounds__(512, 2) void fam_fwd(Params p) {
  __shared__ float xs[NTOK * LDX];        // 25929 f  (101.3 KB) residual stream
  __shared__ float s_m[NTOK];
  __shared__ float s_r[NTOK];
  __shared__ float sc[13312];             // 52 KB scratch: K/V per head, or gate+h-tile+hid-tile

  const int b   = blockIdx.x;
  const int tid = threadIdx.x;

  // ---------------- Phase 0: build embeddings ----------------
  {
    const int e = tid & 127, tl = tid >> 7;       // 4 token-rows per pass, wave-uniform t
    for (int t = tl; t < NTOK; t += 4) {
      float v;
      if (t < NCAT) {
        int idx = p.x_cat[b * (SEQL * NCAT) + (SEQL - 1) * NCAT + t];
        v = p.emb[idx * EDIM + e] + p.emb_bias[t * EDIM + e];
      } else if (t < NCAT + NNUM) {
        int j = t - NCAT;
        float nv = p.x_num[b * (SEQL * NNUM) + (SEQL - 1) * NNUM + j];
        v = p.emb[(NEMBED - NNUM + 1 + j) * EDIM + e] * nv + p.emb_bias[(NCAT + j) * EDIM + e];
      } else if (t < NCAT + NNUM + NENG) {
        int j = t - (NCAT + NNUM);
        float ev = p.x_eng[b * NENG + j];
        v = p.emb_eng[j * EDIM + e] * ev + p.emb_bias_eng[j * EDIM + e];
      } else {
        v = 0.f;                                   // dummy token
      }
      xs[t * LDX + e] = v;
    }
  }
  __syncthreads();

  // ln0 (in place)
  ln_stats(xs, s_m, s_r, tid);
  __syncthreads();
  {
    const int e = tid & 127, tl = tid >> 7;
    for (int t = tl; t < NTOK; t += 4) {
      float m = s_m[t], r = s_r[t];
      xs[t * LDX + e] = (xs[t * LDX + e] - m) * r * p.ln0w[e] + p.ln0b[e];
    }
  }
  __syncthreads();

  const float scale = 0.17677669529663687f;  // 1/sqrt(32)

  // ---------------- Layers ----------------
  for (int li = 0; li < NLAYER; ++li) {
    const float* ln1w = p.ln1w + li * EDIM;
    const float* ln1b = p.ln1b + li * EDIM;
    const float* Wqkv = p.Wqkv + li * 3 * EDIM * EDIM;
    const float* bqkv = p.bqkv + li * 3 * EDIM;
    const float* Wo   = p.Wo   + li * EDIM * EDIM;
    const float* bo   = p.bo   + li * EDIM;
    const float* ln2w = p.ln2w + li * EDIM;
    const float* ln2b = p.ln2b + li * EDIM;
    const float* Wg   = p.Wg   + li * EDIM * NEXPERT;
    const float* bg   = p.bg   + li * NEXPERT;
    const float* W1   = p.W1   + li * NEXPERT * EDIM * FFD;
    const float* b1   = p.b1   + li * NEXPERT * FFD;
    const float* W2   = p.W2   + li * NEXPERT * FFD * EDIM;
    const float* b2   = p.b2   + li * NEXPERT * EDIM;

    // ---- ln1 stats ----
    ln_stats(xs, s_m, s_r, tid);
    __syncthreads();

    float oall[EDIM];  // per-token attention output, all heads, registers only

    float* Ksh = sc;
    float* Vsh = sc + NTOK * KVP;

    // ---- attention: heads fully unrolled so oall indices stay static ----
#pragma unroll
    for (int h = 0; h < NHEAD; ++h) {
      // K/V for this head into LDS (all 512 threads)
      {
        const int d  = tid & 31;
        const int tl = tid >> 5;                // 16 token-rows
        const float* WK = Wqkv + (EDIM     + h * HD + d) * EDIM;
        const float* WV = Wqkv + (2 * EDIM + h * HD + d) * EDIM;
        const float bk = bqkv[EDIM     + h * HD + d];
        const float bv = bqkv[2 * EDIM + h * HD + d];
        for (int t = tl; t < NTOK; t += 16) {
          const float* row = xs + t * LDX;
          float m = s_m[t], r = s_r[t];
          float ak0 = 0.f, ak1 = 0.f, av0 = 0.f, av1 = 0.f;
          for (int e = 0; e < EDIM; e += 2) {
            float h0 = (row[e]     - m) * r * ln1w[e]     + ln1b[e];
            float h1 = (row[e + 1] - m) * r * ln1w[e + 1] + ln1b[e + 1];
            ak0 += h0 * WK[e];     av0 += h0 * WV[e];
            ak1 += h1 * WK[e + 1]; av1 += h1 * WV[e + 1];
          }
          Ksh[t * KVP + d] = ak0 + ak1 + bk;
          Vsh[t * KVP + d] = av0 + av1 + bv;
        }
      }
      __syncthreads();

      // per-token online-softmax attention
      if (tid < NTOK) {
        const int t = tid;
        const float* row = xs + t * LDX;
        float m = s_m[t], r = s_r[t];
        float q[HD];
#pragma unroll
        for (int d2 = 0; d2 < HD; ++d2) q[d2] = 0.f;
        const float* WQ = Wqkv + (h * HD) * EDIM;
        for (int e = 0; e < EDIM; ++e) {
          float hv = (row[e] - m) * r * ln1w[e] + ln1b[e];
#pragma unroll
          for (int d2 = 0; d2 < HD; ++d2) q[d2] += hv * WQ[d2 * EDIM + e];
        }
#pragma unroll
        for (int d2 = 0; d2 < HD; ++d2) q[d2] = (q[d2] + bqkv[h * HD + d2]) * scale;

        float mrun = -INFINITY, denom = 0.f;
#pragma unroll
        for (int d2 = 0; d2 < HD; ++d2) oall[h * HD + d2] = 0.f;

        for (int k = 0; k < NTOK; ++k) {
          const float4* kr = (const float4*)(Ksh + k * KVP);
          float s0 = 0.f, s1 = 0.f, s2 = 0.f, s3 = 0.f;
#pragma unroll
          for (int w = 0; w < 8; w += 2) {
            float4 ka = kr[w], kb = kr[w + 1];
            s0 += q[w * 4 + 0] * ka.x + q[w * 4 + 4] * kb.x;
            s1 += q[w * 4 + 1] * ka.y + q[w * 4 + 5] * kb.y;
            s2 += q[w * 4 + 2] * ka.z + q[w * 4 + 6] * kb.z;
            s3 += q[w * 4 + 3] * ka.w + q[w * 4 + 7] * kb.w;
          }
          float s = (s0 + s1) + (s2 + s3);
          if (s > mrun) {
            float c = __expf(mrun - s);
            mrun = s;
            denom *= c;
#pragma unroll
            for (int d2 = 0; d2 < HD; ++d2) oall[h * HD + d2] *= c;
          }
          float pp = __expf(s - mrun);
          denom += pp;
          const float4* vr = (const float4*)(Vsh + k * KVP);
#pragma unroll
          for (int w = 0; w < 8; ++w) {
            float4 vv = vr[w];
            oall[h * HD + w * 4 + 0] += pp * vv.x;
            oall[h * HD + w * 4 + 1] += pp * vv.y;
            oall[h * HD + w * 4 + 2] += pp * vv.z;
            oall[h * HD + w * 4 + 3] += pp * vv.w;
          }
        }
        float inv = 1.0f / denom;
#pragma unroll
        for (int d2 = 0; d2 < HD; ++d2) oall[h * HD + d2] *= inv;
      }
      __syncthreads();
    }

    // ---- x += o @ Wo^T + bo (per token, oall in registers) ----
    if (tid < NTOK) {
      const int t = tid;
      for (int j = 0; j < EDIM; ++j) {
        const float* wr = Wo + j * EDIM;
        float a0 = 0.f, a1 = 0.f, a2 = 0.f, a3 = 0.f;
#pragma unroll
        for (int d2 = 0; d2 < EDIM; d2 += 4) {
          a0 += oall[d2]     * wr[d2];
          a1 += oall[d2 + 1] * wr[d2 + 1];
          a2 += oall[d2 + 2] * wr[d2 + 2];
          a3 += oall[d2 + 3] * wr[d2 + 3];
        }
        xs[t * LDX + j] += (a0 + a1) + (a2 + a3) + bo[j];
      }
    }
    __syncthreads();

    // ---- ln2 stats ----
    ln_stats(xs, s_m, s_r, tid);
    __syncthreads();

    // ---- gate ----
    float* gbuf = sc;                       // NTOK x 5 (K/V dead now)
    if (tid < NTOK) {
      const int t = tid;
      const float* row = xs + t * LDX;
      float m = s_m[t], r = s_r[t];
      float gl[NEXPERT];
#pragma unroll
      for (int x = 0; x < NEXPERT; ++x) gl[x] = bg[x];
      for (int e = 0; e < EDIM; ++e) {
        float hv = (row[e] - m) * r * ln2w[e] + ln2b[e];
#pragma unroll
        for (int x = 0; x < NEXPERT; ++x) gl[x] += hv * Wg[e * NEXPERT + x];
      }
      float gm = gl[0];
#pragma unroll
      for (int x = 1; x < NEXPERT; ++x) gm = fmaxf(gm, gl[x]);
      float gs = 0.f;
#pragma unroll
      for (int x = 0; x < NEXPERT; ++x) { gl[x] = __expf(gl[x] - gm); gs += gl[x]; }
      float gi = 1.0f / gs;
#pragma unroll
      for (int x = 0; x < NEXPERT; ++x) gbuf[t * NEXPERT + x] = gl[x] * gi;
    }
    __syncthreads();

    // ---- MoE: 32-token tiles ----
    float* hvt  = sc + 1024;                // 32 x 128 (h tile)
    float* hidb = sc + 1024 + 32 * EDIM;    // 32 x 256 (hid tile)
    for (int t0 = 0; t0 < NTOK; t0 += 32) {
      // stage h tile
      for (int idx = tid; idx < 32 * EDIM; idx += 512) {
        int tl = idx >> 7, e = idx & 127;
        int t = t0 + tl;
        float v = 0.f;
        if (t < NTOK) {
          float m = s_m[t], r = s_r[t];
          v = (xs[t * LDX + e] - m) * r * ln2w[e] + ln2b[e];
        }
        hvt[idx] = v;
      }
      __syncthreads();

      float acc2[2][4] = {};                 // gated output accumulator across experts

      for (int x = 0; x < NEXPERT; ++x) {
        // GEMM1: hid = relu(h @ W1_x + b1_x)
        {
          const int fc = tid & 127, tr = tid >> 7;  // 128 f-cols x 4 t-rows
          const float* W1x = W1 + x * EDIM * FFD;
          float a1v[8][2];
#pragma unroll
          for (int ti = 0; ti < 8; ++ti) { a1v[ti][0] = 0.f; a1v[ti][1] = 0.f; }
          for (int e = 0; e < EDIM; ++e) {
            float w0 = W1x[e * FFD + fc];
            float w1 = W1x[e * FFD + fc + 128];
#pragma unroll
            for (int ti = 0; ti < 8; ++ti) {
              float hv = hvt[(tr + 4 * ti) * EDIM + e];   // broadcast
              a1v[ti][0] += hv * w0;
              a1v[ti][1] += hv * w1;
            }
          }
          const float bb0 = b1[x * FFD + fc];
          const float bb1 = b1[x * FFD + fc + 128];
#pragma unroll
          for (int ti = 0; ti < 8; ++ti) {
            int t = tr + 4 * ti;
            hidb[t * FFD + fc]       = fmaxf(a1v[ti][0] + bb0, 0.f);
            hidb[t * FFD + fc + 128] = fmaxf(a1v[ti][1] + bb1, 0.f);
          }
        }
        __syncthreads();

        // GEMM2: eo = hid @ W2_x; acc2 += g_x * (eo + b2_x)
        {
          const int jc = tid & 31, tr = tid >> 5;   // 32 j-cols x 16 t-rows
          const float* W2x = W2 + x * FFD * EDIM;
          float dt[2][4] = {};
          for (int f = 0; f < FFD; ++f) {
            const float* wr = W2x + f * EDIM + jc;
            float w0 = wr[0], w1 = wr[32], w2 = wr[64], w3 = wr[96];
            float h0 = hidb[tr * FFD + f];
            float h1 = hidb[(tr + 16) * FFD + f];
            dt[0][0] += h0 * w0; dt[0][1] += h0 * w1; dt[0][2] += h0 * w2; dt[0][3] += h0 * w3;
            dt[1][0] += h1 * w0; dt[1][1] += h1 * w1; dt[1][2] += h1 * w2; dt[1][3] += h1 * w3;
          }
#pragma unroll
          for (int i2 = 0; i2 < 2; ++i2) {
            int t = t0 + tr + 16 * i2;
            float g = (t < NTOK) ? gbuf[t * NEXPERT + x] : 0.f;
#pragma unroll
            for (int k2 = 0; k2 < 4; ++k2)
              acc2[i2][k2] += g * (dt[i2][k2] + b2[x * EDIM + jc + 32 * k2]);
          }
        }
        __syncthreads();   // hidb reused by next expert
      }

      // residual write-back
      {
        const int jc = tid & 31, tr = tid >> 5;
#pragma unroll
        for (int i2 = 0; i2 < 2; ++i2) {
          int t = t0 + tr + 16 * i2;
          if (t < NTOK) {
#pragma unroll
            for (int k2 = 0; k2 < 4; ++k2)
              xs[t * LDX + jc + 32 * k2] += acc2[i2][k2];
          }
        }
      }
      __syncthreads();     // hvt reuse + next phase reads xs
    }
  }

  // ---------------- output: token 200 ----------------
  if (tid < EDIM) {
    p.out[b * EDIM + tid] = xs[200 * LDX + tid];
  }
}

extern "C" void kernel_launch(void* const* d_in, const int* in_sizes, int n_in,
                              void* d_out, int out_size, void* d_ws, size_t ws_size,
                              hipStream_t stream) {
  (void)in_sizes; (void)n_in; (void)d_ws; (void)ws_size; (void)out_size;
  Params p;
  p.x_cat        = (const int*)  d_in[0];
  p.x_num        = (const float*)d_in[1];
  p.x_eng        = (const float*)d_in[2];
  p.emb          = (const float*)d_in[3];
  p.emb_bias     = (const float*)d_in[4];
  p.emb_eng      = (const float*)d_in[5];
  p.emb_bias_eng = (const float*)d_in[6];
  p.ln0w = (const float*)d_in[7];  p.ln0b = (const float*)d_in[8];
  p.ln1w = (const float*)d_in[9];  p.ln1b = (const float*)d_in[10];
  p.Wqkv = (const float*)d_in[11]; p.bqkv = (const float*)d_in[12];
  p.Wo   = (const float*)d_in[13]; p.bo   = (const float*)d_in[14];
  p.ln2w = (const float*)d_in[15]; p.ln2b = (const float*)d_in[16];
  p.Wg   = (const float*)d_in[17]; p.bg   = (const float*)d_in[18];
  p.W1   = (const float*)d_in[19]; p.b1   = (const float*)d_in[20];
  p.W2   = (const float*)d_in[21]; p.b2   = (const float*)d_in[22];
  p.out  = (float*)d_out;

  hipLaunchKernelGGL(fam_fwd, dim3(NBATCH), dim3(512), 0, stream, p);
}

// Round 3
// 30959.720 us; speedup vs baseline: 1.1898x; 1.1898x over previous
//
#include <hip/hip_runtime.h>
#include <math.h>

#define NTOK 201
#define EDIM 128
#define LDX  132        // multiple of 4 -> 16B-aligned float4 rows
#define NHEAD 4
#define HD   32
#define NLAY 6
#define NEXP 5
#define FFD  256
#define NCAT 53
#define NNUM 47
#define NENG 100
#define NEMB 1352
#define SEQL 51
#define NB   512
#define LN_EPS 1e-5f
#define SCALE 0.17677669529663687f

typedef __attribute__((ext_vector_type(8))) short bfrag;   // 8 bf16 (4 VGPR)
typedef __attribute__((ext_vector_type(4))) float f32x4;   // mfma acc

__device__ __forceinline__ float bf2f(unsigned short u){ return __uint_as_float(((unsigned)u)<<16); }
__device__ __forceinline__ unsigned short f2bf(float f){
  unsigned u = __float_as_uint(f);
  return (unsigned short)((u + 0x7FFFu + ((u>>16)&1u)) >> 16);
}

// ---------------- workspace layout (bytes) ----------------
#define OFF_WF   0u            // WqkvF  [6][384][128] f32  (ln1w folded, q-rows pre-scaled)
#define OFF_C1   1179648u      // c1     [6][384] f32
#define OFF_C2   1188864u      // c2     [6][384] f32
#define OFF_WOT  1198080u      // WoT    [6][128][128] f32  (transposed)
#define OFF_W1H  1591296u      // W1T hi [6][5][256][128] bf16
#define OFF_W1L  3557376u
#define OFF_W2H  5523456u      // W2T hi [6][5][128][256] bf16
#define OFF_W2L  7489536u
#define WS_END   9455616u

// ---------------- prep kernels ----------------
__global__ void prep_qkv(const float* __restrict__ Wqkv, const float* __restrict__ bqkv,
                         const float* __restrict__ ln1w, const float* __restrict__ ln1b,
                         float* __restrict__ WF, float* __restrict__ c1, float* __restrict__ c2){
  int bid = blockIdx.x; int li = bid / 384; int n = bid % 384; int e = threadIdx.x;
  float w  = Wqkv[(size_t)bid*128 + e];
  float lw = ln1w[li*128+e], lb = ln1b[li*128+e];
  float sc = (n < 128) ? SCALE : 1.0f;      // fold softmax scale into Q rows
  float wf = w*lw*sc;
  WF[(size_t)bid*128+e] = wf;
  __shared__ float r1[128], r2[128];
  r1[e] = wf; r2[e] = w*lb*sc;
  __syncthreads();
  if (e == 0){
    float a=0.f, b=0.f;
    for (int i=0;i<128;++i){ a+=r1[i]; b+=r2[i]; }
    c1[bid]=a; c2[bid]=b + bqkv[bid]*sc;
  }
}

__global__ void prep_wo(const float* __restrict__ Wo, float* __restrict__ WoT){
  int idx = blockIdx.x*blockDim.x + threadIdx.x;
  if (idx >= 6*128*128) return;
  int li = idx >> 14; int j = (idx >> 7) & 127; int d = idx & 127;
  WoT[(size_t)(li*128+d)*128 + j] = Wo[idx];
}

__global__ void prep_moe(const float* __restrict__ W1, const float* __restrict__ W2,
                         unsigned short* __restrict__ W1h, unsigned short* __restrict__ W1l,
                         unsigned short* __restrict__ W2h, unsigned short* __restrict__ W2l){
  const int Ntot = 6*5*128*256;
  for (int idx = blockIdx.x*blockDim.x + threadIdx.x; idx < Ntot; idx += gridDim.x*blockDim.x){
    // W1 flat = [lx][e][f] -> store [lx][f][e]
    int lx = idx / 32768; int rem = idx & 32767; int e = rem >> 8; int f = rem & 255;
    float w = W1[idx];
    unsigned short h = f2bf(w); unsigned short l = f2bf(w - bf2f(h));
    size_t o1 = (size_t)(lx*256+f)*128 + e;
    W1h[o1] = h; W1l[o1] = l;
    // W2 flat = [lx][f][e] -> store [lx][e][f]
    int f2 = (idx >> 7) & 255; int e2 = idx & 127;
    float w2 = W2[idx];
    unsigned short h2 = f2bf(w2); unsigned short l2 = f2bf(w2 - bf2f(h2));
    size_t o2 = (size_t)(lx*128+e2)*256 + f2;
    W2h[o2] = h2; W2l[o2] = l2;
  }
}

// ---------------- main kernel ----------------
struct Params {
  const int*   x_cat;
  const float* x_num;
  const float* x_eng;
  const float* emb;
  const float* emb_bias;
  const float* emb_eng;
  const float* emb_bias_eng;
  const float* ln0w; const float* ln0b;
  const float* ln2w; const float* ln2b;
  const float* bo;
  const float* Wg;   const float* bg;
  const float* b1;   const float* b2;
  // ws-derived
  const float* WF; const float* c1; const float* c2; const float* WoT;
  const unsigned short* W1h; const unsigned short* W1l;
  const unsigned short* W2h; const unsigned short* W2l;
  float* out;
};

__device__ __forceinline__ void ln_stats(const float* xs, float* s_m, float* s_r, int tid){
  if (tid < NTOK){
    const float* row = xs + tid*LDX;
    float s0=0,s1=0,s2=0,s3=0;
    for (int e=0;e<EDIM;e+=4){ s0+=row[e]; s1+=row[e+1]; s2+=row[e+2]; s3+=row[e+3]; }
    float m = (s0+s1+s2+s3)*(1.0f/EDIM);
    float v0=0,v1=0,v2=0,v3=0;
    for (int e=0;e<EDIM;e+=4){
      float d0=row[e]-m,d1=row[e+1]-m,d2=row[e+2]-m,d3=row[e+3]-m;
      v0+=d0*d0; v1+=d1*d1; v2+=d2*d2; v3+=d3*d3;
    }
    s_m[tid]=m; s_r[tid]=1.0f/sqrtf((v0+v1+v2+v3)*(1.0f/EDIM)+LN_EPS);
  }
}

__global__ __launch_bounds__(512, 2) void fam_fwd(Params p){
  __shared__ float xs[NTOK*LDX];          // 106,128 B
  __shared__ float s_m[NTOK], s_r[NTOK];  // 1,608 B
  __shared__ __align__(16) char scb[53184];

  const int b = blockIdx.x, tid = threadIdx.x;
  const int lane = tid & 63, wv = tid >> 6;

  // ---- Phase 0: embeddings ----
  {
    const int e = tid & 127, tl = tid >> 7;
    for (int t = tl; t < NTOK; t += 4){
      float v;
      if (t < NCAT){
        int idx = p.x_cat[b*(SEQL*NCAT) + (SEQL-1)*NCAT + t];
        v = p.emb[idx*EDIM+e] + p.emb_bias[t*EDIM+e];
      } else if (t < NCAT+NNUM){
        int j = t - NCAT;
        float nv = p.x_num[b*(SEQL*NNUM)+(SEQL-1)*NNUM+j];
        v = p.emb[(NEMB-NNUM+1+j)*EDIM+e]*nv + p.emb_bias[(NCAT+j)*EDIM+e];
      } else if (t < NCAT+NNUM+NENG){
        int j = t - (NCAT+NNUM);
        float ev = p.x_eng[b*NENG+j];
        v = p.emb_eng[j*EDIM+e]*ev + p.emb_bias_eng[j*EDIM+e];
      } else v = 0.f;
      xs[t*LDX+e] = v;
    }
  }
  __syncthreads();
  ln_stats(xs, s_m, s_r, tid);
  __syncthreads();
  {
    const int e = tid & 127, tl = tid >> 7;
    for (int t = tl; t < NTOK; t += 4){
      float m = s_m[t], r = s_r[t];
      xs[t*LDX+e] = (xs[t*LDX+e]-m)*r*p.ln0w[e] + p.ln0b[e];
    }
  }
  __syncthreads();

  // attn scratch pointers
  unsigned short* Kb = (unsigned short*)scb;            // [201][32] bf16
  unsigned short* Vb = (unsigned short*)(scb + 12864);  // [201][32] bf16
  float*          Qt = (float*)(scb + 25728);           // [32][33] f32 (also o-tile)
  unsigned short* Sb = (unsigned short*)(scb + 29952);  // [32][204] bf16
  float*          red = (float*)(scb + 43008);          // [8][33]
  float*          mrow = (float*)(scb + 44064);         // [32]
  float*          dsum = (float*)(scb + 44192);         // [32]
  // moe scratch pointers
  unsigned short* Ahi = (unsigned short*)scb;           // frag-packed 32x128
  unsigned short* Alo = (unsigned short*)(scb + 8192);
  unsigned short* Hh  = (unsigned short*)(scb + 16384); // frag-packed 32x256
  unsigned short* Hl  = (unsigned short*)(scb + 32768);
  float*          gateb = (float*)(scb + 49152);        // [201][5]

  for (int li = 0; li < NLAY; ++li){
    const float* WF  = p.WF  + (size_t)li*384*128;
    const float* c1  = p.c1  + li*384;
    const float* c2  = p.c2  + li*384;
    const float* WoT = p.WoT + (size_t)li*128*128;
    const float* ln2w = p.ln2w + li*EDIM;
    const float* ln2b = p.ln2b + li*EDIM;
    const float* bo   = p.bo + li*EDIM;
    const float* Wg   = p.Wg + li*EDIM*NEXP;
    const float* bg   = p.bg + li*NEXP;
    const float* b1g  = p.b1 + li*NEXP*FFD;
    const float* b2g  = p.b2 + li*NEXP*EDIM;

    ln_stats(xs, s_m, s_r, tid);   // ln1 stats
    __syncthreads();

    float accA[7][8] = {};         // attention+Wo delta, static-indexed

    for (int h = 0; h < NHEAD; ++h){
      // ---- K/V staging (folded LN), bf16 to LDS ----
      {
        const int d = tid & 31, tg = tid >> 5;
        const float* WK = WF + (size_t)(128 + h*HD + d)*128;
        const float* WV = WF + (size_t)(256 + h*HD + d)*128;
        float aK[13], aV[13];
#pragma unroll
        for (int i=0;i<13;++i){ aK[i]=0.f; aV[i]=0.f; }
        for (int e4=0;e4<32;++e4){
          float4 wk = *(const float4*)(WK + 4*e4);
          float4 wvv = *(const float4*)(WV + 4*e4);
#pragma unroll
          for (int i=0;i<13;++i){
            int t = tg + 16*i; int tc = (t < NTOK) ? t : (NTOK-1);   // clamp: no garbage reads
            float4 xv = *(const float4*)(&xs[tc*LDX + 4*e4]);
            aK[i] += xv.x*wk.x + xv.y*wk.y + xv.z*wk.z + xv.w*wk.w;
            aV[i] += xv.x*wvv.x + xv.y*wvv.y + xv.z*wvv.z + xv.w*wvv.w;
          }
        }
        float c1k = c1[128+h*HD+d], c2k = c2[128+h*HD+d];
        float c1v = c1[256+h*HD+d], c2v = c2[256+h*HD+d];
#pragma unroll
        for (int i=0;i<13;++i){
          int t = tg + 16*i;
          if (t < NTOK){
            float m = s_m[t], r = s_r[t];
            Kb[t*32+d] = f2bf(r*aK[i] - r*m*c1k + c2k);
            Vb[t*32+d] = f2bf(r*aV[i] - r*m*c1v + c2v);
          }
        }
      }
      __syncthreads();

#pragma unroll
      for (int qt = 0; qt < 7; ++qt){
        const int t0 = qt*32;
        // ---- Q tile (fp32) ----
        {
          const int q = tid & 31, dg = tid >> 5;
          int t = t0 + q; int tc = (t < NTOK) ? t : (NTOK-1);        // clamp
          float m = s_m[tc], r = s_r[tc];
          const float* r0 = WF + (size_t)(h*HD + dg)*128;
          const float* r1 = r0 + 16*128;
          float a0=0.f, a1=0.f;
          for (int e4=0;e4<32;++e4){
            float4 xv = *(const float4*)(&xs[tc*LDX + 4*e4]);
            float4 w0 = *(const float4*)(r0 + 4*e4);
            float4 w1 = *(const float4*)(r1 + 4*e4);
            a0 += xv.x*w0.x + xv.y*w0.y + xv.z*w0.z + xv.w*w0.w;
            a1 += xv.x*w1.x + xv.y*w1.y + xv.z*w1.z + xv.w*w1.w;
          }
          int n0 = h*HD + dg, n1 = n0 + 16;
          Qt[q*33+dg]    = r*a0 - r*m*c1[n0] + c2[n0];
          Qt[q*33+dg+16] = r*a1 - r*m*c1[n1] + c2[n1];
        }
        __syncthreads();
        // ---- scores + row max ----
        {
          const int q = tid & 31, kg = tid >> 5;
          float qreg[32];
#pragma unroll
          for (int c=0;c<32;++c) qreg[c] = Qt[q*33+c];
          float pmax = -INFINITY;
          for (int j=0;j<13;++j){
            int k = kg + 16*j;
            if (k < NTOK){
              const unsigned short* kr = Kb + k*32;
              float s = 0.f;
#pragma unroll
              for (int c=0;c<32;++c) s += qreg[c]*bf2f(kr[c]);
              pmax = fmaxf(pmax, s);
              Sb[q*204+k] = f2bf(s);
            }
          }
          pmax = fmaxf(pmax, __shfl_xor(pmax, 32));
          if (!(tid & 32)) red[(tid>>6)*33 + q] = pmax;
        }
        __syncthreads();
        if (tid < 32){
          float m = red[tid];
#pragma unroll
          for (int w=1;w<8;++w) m = fmaxf(m, red[w*33+tid]);
          mrow[tid] = m;
        }
        __syncthreads();
        // ---- exp + row sum ----
        {
          const int q = tid & 31, kg = tid >> 5;
          float mr = mrow[q];
          float psum = 0.f;
          for (int j=0;j<13;++j){
            int k = kg + 16*j;
            if (k < NTOK){
              float sv = bf2f(Sb[q*204+k]);
              float pe = __expf(sv - mr);
              psum += pe;
              Sb[q*204+k] = f2bf(pe);
            }
          }
          psum += __shfl_xor(psum, 32);
          if (!(tid & 32)) red[(tid>>6)*33 + q] = psum;
        }
        __syncthreads();
        if (tid < 32){
          float s = red[tid];
#pragma unroll
          for (int w=1;w<8;++w) s += red[w*33+tid];
          dsum[tid] = s;
        }
        __syncthreads();
        // ---- PV -> o tile (overwrite Qt) ----
        {
          const int q = tid & 31, dg = tid >> 5;
          float o0=0.f, o1=0.f;
          const unsigned short* sp = Sb + q*204;
          for (int k=0;k<NTOK;++k){
            float pv = bf2f(sp[k]);
            o0 += pv*bf2f(Vb[k*32+dg]);
            o1 += pv*bf2f(Vb[k*32+dg+16]);
          }
          float inv = 1.0f/dsum[q];
          Qt[q*33+dg]    = o0*inv;
          Qt[q*33+dg+16] = o1*inv;
        }
        __syncthreads();
        // ---- fold Wo into accA ----
        {
          const int trow = tid & 31, jb = tid >> 5;
          const float* wbase = WoT + (size_t)(h*HD)*128 + jb*8;
          for (int d=0;d<HD;++d){
            float ov = Qt[trow*33+d];
            float4 w0 = *(const float4*)(wbase + (size_t)d*128);
            float4 w1 = *(const float4*)(wbase + (size_t)d*128 + 4);
            accA[qt][0] += ov*w0.x; accA[qt][1] += ov*w0.y;
            accA[qt][2] += ov*w0.z; accA[qt][3] += ov*w0.w;
            accA[qt][4] += ov*w1.x; accA[qt][5] += ov*w1.y;
            accA[qt][6] += ov*w1.z; accA[qt][7] += ov*w1.w;
          }
        }
        __syncthreads();
      } // qt
    } // h

    // ---- apply attention delta + bo ----
    {
      const int trow = tid & 31, jb = tid >> 5;
      float4 b0 = *(const float4*)(bo + jb*8);
      float4 b1v = *(const float4*)(bo + jb*8 + 4);
      float bov[8] = {b0.x,b0.y,b0.z,b0.w,b1v.x,b1v.y,b1v.z,b1v.w};
#pragma unroll
      for (int qt=0;qt<7;++qt){
        int t = qt*32 + trow;
        if (t < NTOK){
          float* xr = &xs[t*LDX + jb*8];
#pragma unroll
          for (int jj=0;jj<8;++jj) xr[jj] += accA[qt][jj] + bov[jj];
        }
      }
    }
    __syncthreads();

    ln_stats(xs, s_m, s_r, tid);   // ln2 stats
    __syncthreads();

    // ---- gate (softmax over 5 experts) ----
    if (tid < NTOK){
      const float* row = xs + tid*LDX;
      float m = s_m[tid], r = s_r[tid];
      float gl[NEXP];
#pragma unroll
      for (int x=0;x<NEXP;++x) gl[x] = bg[x];
      for (int e=0;e<EDIM;++e){
        float hv = (row[e]-m)*r*ln2w[e] + ln2b[e];
#pragma unroll
        for (int x=0;x<NEXP;++x) gl[x] += hv*Wg[e*NEXP+x];
      }
      float gm = gl[0];
#pragma unroll
      for (int x=1;x<NEXP;++x) gm = fmaxf(gm, gl[x]);
      float gs = 0.f;
#pragma unroll
      for (int x=0;x<NEXP;++x){ gl[x] = __expf(gl[x]-gm); gs += gl[x]; }
      float gi = 1.0f/gs;
#pragma unroll
      for (int x=0;x<NEXP;++x) gateb[tid*NEXP+x] = gl[x]*gi;
    }
    __syncthreads();

    // ---- MoE: MFMA, 32-token tiles, gate folded into hid, acc across experts ----
    for (int t0 = 0; t0 < NTOK; t0 += 32){
      // A-stage: ln2(x) split hi/lo bf16, frag-packed (dest = tid*16B, linear)
      {
        int mf = tid >> 8;
        int row = (tid & 15) + 16*mf;
        int kb  = ((tid>>6)&3)*32 + 8*((tid>>4)&3);
        int t = t0 + row;
        union { unsigned short u[8]; bfrag v; } hu, lu;
        if (t < NTOK){
          float m = s_m[t], r = s_r[t];
          const float* xr = &xs[t*LDX + kb];
          float4 a = *(const float4*)xr;
          float4 bq = *(const float4*)(xr+4);
          float4 w0 = *(const float4*)(ln2w + kb);
          float4 w1 = *(const float4*)(ln2w + kb + 4);
          float4 bb0 = *(const float4*)(ln2b + kb);
          float4 bb1 = *(const float4*)(ln2b + kb + 4);
          float vv[8] = {(a.x-m)*r*w0.x+bb0.x, (a.y-m)*r*w0.y+bb0.y,
                         (a.z-m)*r*w0.z+bb0.z, (a.w-m)*r*w0.w+bb0.w,
                         (bq.x-m)*r*w1.x+bb1.x, (bq.y-m)*r*w1.y+bb1.y,
                         (bq.z-m)*r*w1.z+bb1.z, (bq.w-m)*r*w1.w+bb1.w};
#pragma unroll
          for (int j=0;j<8;++j){
            unsigned short hb = f2bf(vv[j]);
            hu.u[j] = hb;
            lu.u[j] = f2bf(vv[j] - bf2f(hb));
          }
        } else {
#pragma unroll
          for (int j=0;j<8;++j){ hu.u[j]=0; lu.u[j]=0; }
        }
        *(bfrag*)(Ahi + tid*8) = hu.v;
        *(bfrag*)(Alo + tid*8) = lu.v;
      }
      __syncthreads();

      f32x4 acc2[2];
      acc2[0] = (f32x4){0.f,0.f,0.f,0.f};
      acc2[1] = (f32x4){0.f,0.f,0.f,0.f};

      for (int x = 0; x < NEXP; ++x){
        const unsigned short* W1hx = p.W1h + (size_t)(li*NEXP+x)*FFD*EDIM;
        const unsigned short* W1lx = p.W1l + (size_t)(li*NEXP+x)*FFD*EDIM;
        const unsigned short* W2hx = p.W2h + (size_t)(li*NEXP+x)*EDIM*FFD;
        const unsigned short* W2lx = p.W2l + (size_t)(li*NEXP+x)*EDIM*FFD;

        // GEMM1: [32x128] @ [128x256] -> wave owns 32 n-cols
        f32x4 acc1[2][2];
#pragma unroll
        for (int i=0;i<2;++i){ acc1[i][0]=(f32x4){0,0,0,0}; acc1[i][1]=(f32x4){0,0,0,0}; }
#pragma unroll
        for (int kf=0;kf<4;++kf){
          bfrag ah[2], al[2], bh[2], bl[2];
#pragma unroll
          for (int mf=0;mf<2;++mf){
            ah[mf] = *(const bfrag*)(Ahi + ((mf*4+kf)*64 + lane)*8);
            al[mf] = *(const bfrag*)(Alo + ((mf*4+kf)*64 + lane)*8);
          }
#pragma unroll
          for (int nfl=0;nfl<2;++nfl){
            size_t n = (size_t)((wv*2+nfl)*16 + (lane&15));
            size_t off = n*128 + kf*32 + 8*(lane>>4);
            bh[nfl] = *(const bfrag*)(W1hx + off);
            bl[nfl] = *(const bfrag*)(W1lx + off);
          }
#pragma unroll
          for (int mf=0;mf<2;++mf)
#pragma unroll
            for (int nfl=0;nfl<2;++nfl){
              acc1[mf][nfl] = __builtin_amdgcn_mfma_f32_16x16x32_bf16(ah[mf], bh[nfl], acc1[mf][nfl], 0,0,0);
              acc1[mf][nfl] = __builtin_amdgcn_mfma_f32_16x16x32_bf16(ah[mf], bl[nfl], acc1[mf][nfl], 0,0,0);
              acc1[mf][nfl] = __builtin_amdgcn_mfma_f32_16x16x32_bf16(al[mf], bh[nfl], acc1[mf][nfl], 0,0,0);
            }
        }
        // epilogue: bias, relu, gate-scale, split, scatter to hid frag layout
        {
          int c = lane & 15;
#pragma unroll
          for (int nfl=0;nfl<2;++nfl){
            int n = (wv*2+nfl)*16 + c;
            float bb = b1g[x*FFD + n];
            int lane_t_base = 16*(2*nfl + (c>>3));
            int jcol = c & 7;
#pragma unroll
            for (int mf=0;mf<2;++mf){
#pragma unroll
              for (int reg=0;reg<4;++reg){
                int msub = (lane>>4)*4 + reg;
                int t = t0 + mf*16 + msub;
                float g = (t < NTOK) ? gateb[t*NEXP+x] : 0.f;
                float v = fmaxf(acc1[mf][nfl][reg] + bb, 0.f) * g;
                unsigned short hb = f2bf(v);
                unsigned short lb = f2bf(v - bf2f(hb));
                int idx = ((mf*8 + wv)*64 + msub + lane_t_base)*8 + jcol;
                Hh[idx] = hb; Hl[idx] = lb;
              }
            }
          }
        }
        __syncthreads();

        // GEMM2: [32x256] @ [256x128] -> wave owns 16 n-cols; acc across experts
#pragma unroll
        for (int kf=0;kf<8;++kf){
          bfrag hh[2], hl[2];
#pragma unroll
          for (int mf=0;mf<2;++mf){
            hh[mf] = *(const bfrag*)(Hh + ((mf*8+kf)*64 + lane)*8);
            hl[mf] = *(const bfrag*)(Hl + ((mf*8+kf)*64 + lane)*8);
          }
          size_t off = (size_t)(wv*16 + (lane&15))*256 + kf*32 + 8*(lane>>4);
          bfrag wh = *(const bfrag*)(W2hx + off);
          bfrag wl = *(const bfrag*)(W2lx + off);
#pragma unroll
          for (int mf=0;mf<2;++mf){
            acc2[mf] = __builtin_amdgcn_mfma_f32_16x16x32_bf16(hh[mf], wh, acc2[mf], 0,0,0);
            acc2[mf] = __builtin_amdgcn_mfma_f32_16x16x32_bf16(hh[mf], wl, acc2[mf], 0,0,0);
            acc2[mf] = __builtin_amdgcn_mfma_f32_16x16x32_bf16(hl[mf], wh, acc2[mf], 0,0,0);
          }
        }
        __syncthreads();   // hid free for next expert's epilogue
      } // x

      // tile epilogue: + sum_x g*b2, RMW xs
      {
        int c = lane & 15;
        int n = wv*16 + c;
#pragma unroll
        for (int mf=0;mf<2;++mf){
#pragma unroll
          for (int reg=0;reg<4;++reg){
            int t = t0 + mf*16 + (lane>>4)*4 + reg;
            if (t < NTOK){
              float bs = 0.f;
#pragma unroll
              for (int x=0;x<NEXP;++x) bs += gateb[t*NEXP+x]*b2g[x*EDIM+n];
              xs[t*LDX+n] += acc2[mf][reg] + bs;
            }
          }
        }
      }
      __syncthreads();     // Ahi/Alo reuse next tile
    } // tiles
  } // layers

  if (tid < EDIM) p.out[b*EDIM + tid] = xs[200*LDX + tid];
}

extern "C" void kernel_launch(void* const* d_in, const int* in_sizes, int n_in,
                              void* d_out, int out_size, void* d_ws, size_t ws_size,
                              hipStream_t stream) {
  (void)in_sizes; (void)n_in; (void)out_size; (void)ws_size;
  char* ws = (char*)d_ws;

  const float* Wqkv = (const float*)d_in[11];
  const float* bqkv = (const float*)d_in[12];
  const float* ln1w = (const float*)d_in[9];
  const float* ln1b = (const float*)d_in[10];
  const float* Wo   = (const float*)d_in[13];
  const float* W1   = (const float*)d_in[19];
  const float* W2   = (const float*)d_in[21];

  hipLaunchKernelGGL(prep_qkv, dim3(6*384), dim3(128), 0, stream,
                     Wqkv, bqkv, ln1w, ln1b,
                     (float*)(ws+OFF_WF), (float*)(ws+OFF_C1), (float*)(ws+OFF_C2));
  hipLaunchKernelGGL(prep_wo, dim3(384), dim3(256), 0, stream, Wo, (float*)(ws+OFF_WOT));
  hipLaunchKernelGGL(prep_moe, dim3(3840), dim3(256), 0, stream, W1, W2,
                     (unsigned short*)(ws+OFF_W1H), (unsigned short*)(ws+OFF_W1L),
                     (unsigned short*)(ws+OFF_W2H), (unsigned short*)(ws+OFF_W2L));

  Params p;
  p.x_cat        = (const int*)  d_in[0];
  p.x_num        = (const float*)d_in[1];
  p.x_eng        = (const float*)d_in[2];
  p.emb          = (const float*)d_in[3];
  p.emb_bias     = (const float*)d_in[4];
  p.emb_eng      = (const float*)d_in[5];
  p.emb_bias_eng = (const float*)d_in[6];
  p.ln0w = (const float*)d_in[7];  p.ln0b = (const float*)d_in[8];
  p.ln2w = (const float*)d_in[15]; p.ln2b = (const float*)d_in[16];
  p.bo   = (const float*)d_in[14];
  p.Wg   = (const float*)d_in[17]; p.bg = (const float*)d_in[18];
  p.b1   = (const float*)d_in[20]; p.b2 = (const float*)d_in[22];
  p.WF  = (const float*)(ws+OFF_WF);
  p.c1  = (const float*)(ws+OFF_C1);
  p.c2  = (const float*)(ws+OFF_C2);
  p.WoT = (const float*)(ws+OFF_WOT);
  p.W1h = (const unsigned short*)(ws+OFF_W1H);
  p.W1l = (const unsigned short*)(ws+OFF_W1L);
  p.W2h = (const unsigned short*)(ws+OFF_W2H);
  p.W2l = (const unsigned short*)(ws+OFF_W2L);
  p.out = (float*)d_out;

  hipLaunchKernelGGL(fam_fwd, dim3(NB), dim3(512), 0, stream, p);
}

// Round 4
// 11232.898 us; speedup vs baseline: 3.2792x; 2.7562x over previous
//
#include <hip/hip_runtime.h>
#include <math.h>

#define NTOK 201
#define EDIM 128
#define LDX  132        // multiple of 4 -> 16B-aligned float4 rows
#define NHEAD 4
#define HD   32
#define NLAY 6
#define NEXP 5
#define FFD  256
#define NCAT 53
#define NNUM 47
#define NENG 100
#define NEMB 1352
#define SEQL 51
#define NB   512
#define LN_EPS 1e-5f
#define SCALE 0.17677669529663687f

typedef __attribute__((ext_vector_type(8))) short bfrag;   // 8 bf16 (4 VGPR)
typedef __attribute__((ext_vector_type(4))) float f32x4;   // mfma acc
typedef __attribute__((ext_vector_type(8))) unsigned short u16x8;
typedef __attribute__((ext_vector_type(4))) unsigned short u16x4;

__device__ __forceinline__ float bf2f(unsigned short u){ return __uint_as_float(((unsigned)u)<<16); }
__device__ __forceinline__ unsigned short f2bf(float f){
  unsigned u = __float_as_uint(f);
  return (unsigned short)((u + 0x7FFFu + ((u>>16)&1u)) >> 16);
}

// ---------------- workspace layout (bytes) ----------------
#define OFF_WF   0u            // WqkvF  [6][384][128] f32  (ln1w folded, q-rows pre-scaled)
#define OFF_C1   1179648u      // c1     [6][384] f32
#define OFF_C2   1188864u      // c2     [6][384] f32
#define OFF_WOT  1198080u      // WoT    [6][128][128] f32  (transposed)
#define OFF_W1H  1591296u      // W1T hi [6][5][256][128] bf16
#define OFF_W1L  3557376u
#define OFF_W2H  5523456u      // W2T hi [6][5][128][256] bf16
#define OFF_W2L  7489536u

// ---------------- prep kernels ----------------
__global__ void prep_qkv(const float* __restrict__ Wqkv, const float* __restrict__ bqkv,
                         const float* __restrict__ ln1w, const float* __restrict__ ln1b,
                         float* __restrict__ WF, float* __restrict__ c1, float* __restrict__ c2){
  int bid = blockIdx.x; int li = bid / 384; int n = bid % 384; int e = threadIdx.x;
  float w  = Wqkv[(size_t)bid*128 + e];
  float lw = ln1w[li*128+e], lb = ln1b[li*128+e];
  float sc = (n < 128) ? SCALE : 1.0f;      // fold softmax scale into Q rows
  float wf = w*lw*sc;
  WF[(size_t)bid*128+e] = wf;
  __shared__ float r1[128], r2[128];
  r1[e] = wf; r2[e] = w*lb*sc;
  __syncthreads();
  if (e == 0){
    float a=0.f, b=0.f;
    for (int i=0;i<128;++i){ a+=r1[i]; b+=r2[i]; }
    c1[bid]=a; c2[bid]=b + bqkv[bid]*sc;
  }
}

__global__ void prep_wo(const float* __restrict__ Wo, float* __restrict__ WoT){
  int idx = blockIdx.x*blockDim.x + threadIdx.x;
  if (idx >= 6*128*128) return;
  int li = idx >> 14; int j = (idx >> 7) & 127; int d = idx & 127;
  WoT[(size_t)(li*128+d)*128 + j] = Wo[idx];
}

__global__ void prep_moe(const float* __restrict__ W1, const float* __restrict__ W2,
                         unsigned short* __restrict__ W1h, unsigned short* __restrict__ W1l,
                         unsigned short* __restrict__ W2h, unsigned short* __restrict__ W2l){
  const int Ntot = 6*5*128*256;
  for (int idx = blockIdx.x*blockDim.x + threadIdx.x; idx < Ntot; idx += gridDim.x*blockDim.x){
    // W1 flat = [lx][e][f] -> store [lx][f][e]
    int lx = idx / 32768; int rem = idx & 32767; int e = rem >> 8; int f = rem & 255;
    float w = W1[idx];
    unsigned short h = f2bf(w); unsigned short l = f2bf(w - bf2f(h));
    size_t o1 = (size_t)(lx*256+f)*128 + e;
    W1h[o1] = h; W1l[o1] = l;
    // W2 flat = [lx][f][e] -> store [lx][e][f]
    int f2 = (idx >> 7) & 255; int e2 = idx & 127;
    float w2 = W2[idx];
    unsigned short h2 = f2bf(w2); unsigned short l2 = f2bf(w2 - bf2f(h2));
    size_t o2 = (size_t)(lx*128+e2)*256 + f2;
    W2h[o2] = h2; W2l[o2] = l2;
  }
}

// ---------------- main kernel ----------------
struct Params {
  const int*   x_cat;
  const float* x_num;
  const float* x_eng;
  const float* emb;
  const float* emb_bias;
  const float* emb_eng;
  const float* emb_bias_eng;
  const float* ln0w; const float* ln0b;
  const float* ln2w; const float* ln2b;
  const float* bo;
  const float* Wg;   const float* bg;
  const float* b1;   const float* b2;
  // ws-derived
  const float* WF; const float* c1; const float* c2; const float* WoT;
  const unsigned short* W1h; const unsigned short* W1l;
  const unsigned short* W2h; const unsigned short* W2l;
  float* out;
};

__device__ __forceinline__ void ln_stats(const float* xs, float* s_m, float* s_r, int tid){
  if (tid < NTOK){
    const float* row = xs + tid*LDX;
    float s0=0,s1=0,s2=0,s3=0;
    for (int e=0;e<EDIM;e+=4){ s0+=row[e]; s1+=row[e+1]; s2+=row[e+2]; s3+=row[e+3]; }
    float m = (s0+s1+s2+s3)*(1.0f/EDIM);
    float v0=0,v1=0,v2=0,v3=0;
    for (int e=0;e<EDIM;e+=4){
      float d0=row[e]-m,d1=row[e+1]-m,d2=row[e+2]-m,d3=row[e+3]-m;
      v0+=d0*d0; v1+=d1*d1; v2+=d2*d2; v3+=d3*d3;
    }
    s_m[tid]=m; s_r[tid]=1.0f/sqrtf((v0+v1+v2+v3)*(1.0f/EDIM)+LN_EPS);
  }
}

__global__ __launch_bounds__(512, 1) void fam_fwd(Params p){
  __shared__ float xs[NTOK*LDX];          // 106,128 B
  __shared__ float s_m[NTOK], s_r[NTOK];  // 1,608 B
  __shared__ __align__(16) char scb[53184];

  const int b = blockIdx.x, tid = threadIdx.x;
  const int lane = tid & 63, wv = tid >> 6;

  // ---- Phase 0: embeddings ----
  {
    const int e = tid & 127, tl = tid >> 7;
    for (int t = tl; t < NTOK; t += 4){
      float v;
      if (t < NCAT){
        int idx = p.x_cat[b*(SEQL*NCAT) + (SEQL-1)*NCAT + t];
        v = p.emb[idx*EDIM+e] + p.emb_bias[t*EDIM+e];
      } else if (t < NCAT+NNUM){
        int j = t - NCAT;
        float nv = p.x_num[b*(SEQL*NNUM)+(SEQL-1)*NNUM+j];
        v = p.emb[(NEMB-NNUM+1+j)*EDIM+e]*nv + p.emb_bias[(NCAT+j)*EDIM+e];
      } else if (t < NCAT+NNUM+NENG){
        int j = t - (NCAT+NNUM);
        float ev = p.x_eng[b*NENG+j];
        v = p.emb_eng[j*EDIM+e]*ev + p.emb_bias_eng[j*EDIM+e];
      } else v = 0.f;
      xs[t*LDX+e] = v;
    }
  }
  __syncthreads();
  ln_stats(xs, s_m, s_r, tid);
  __syncthreads();
  {
    const int e = tid & 127, tl = tid >> 7;
    for (int t = tl; t < NTOK; t += 4){
      float m = s_m[t], r = s_r[t];
      xs[t*LDX+e] = (xs[t*LDX+e]-m)*r*p.ln0w[e] + p.ln0b[e];
    }
  }
  __syncthreads();

  // attn scratch pointers
  unsigned short* Kb = (unsigned short*)scb;            // [201][32] bf16
  unsigned short* Vb = (unsigned short*)(scb + 12864);  // [201][32] bf16
  float*          Qt = (float*)(scb + 25728);           // [32][33] f32 (also o-tile)
  unsigned short* Sb = (unsigned short*)(scb + 29952);  // [32][204] bf16
  float*          red = (float*)(scb + 43008);          // [8][33]
  float*          mrow = (float*)(scb + 44064);         // [32]
  float*          dsum = (float*)(scb + 44192);         // [32]
  // moe scratch pointers
  unsigned short* Ahi = (unsigned short*)scb;           // frag-packed 32x128
  unsigned short* Alo = (unsigned short*)(scb + 8192);
  unsigned short* Hh  = (unsigned short*)(scb + 16384); // frag-packed 32x256
  unsigned short* Hl  = (unsigned short*)(scb + 32768);
  float*          gateb = (float*)(scb + 49152);        // [201][5]

  for (int li = 0; li < NLAY; ++li){
    const float* WF  = p.WF  + (size_t)li*384*128;
    const float* c1  = p.c1  + li*384;
    const float* c2  = p.c2  + li*384;
    const float* WoT = p.WoT + (size_t)li*128*128;
    const float* ln2w = p.ln2w + li*EDIM;
    const float* ln2b = p.ln2b + li*EDIM;
    const float* bo   = p.bo + li*EDIM;
    const float* Wg   = p.Wg + li*EDIM*NEXP;
    const float* bg   = p.bg + li*NEXP;
    const float* b1g  = p.b1 + li*NEXP*FFD;
    const float* b2g  = p.b2 + li*NEXP*EDIM;

    ln_stats(xs, s_m, s_r, tid);   // ln1 stats
    __syncthreads();

    float accA[7][8] = {};         // attention+Wo delta, static-indexed

    for (int h = 0; h < NHEAD; ++h){
      // ---- K/V staging (folded LN), bf16 to LDS ----
      {
        const int d = tid & 31, tg = tid >> 5;
        const float* WK = WF + (size_t)(128 + h*HD + d)*128;
        const float* WV = WF + (size_t)(256 + h*HD + d)*128;
        float aK[13], aV[13];
#pragma unroll
        for (int i=0;i<13;++i){ aK[i]=0.f; aV[i]=0.f; }
        for (int e4=0;e4<32;++e4){
          float4 wk = *(const float4*)(WK + 4*e4);
          float4 wvv = *(const float4*)(WV + 4*e4);
#pragma unroll
          for (int i=0;i<13;++i){
            int t = tg + 16*i; int tc = (t < NTOK) ? t : (NTOK-1);   // clamp: no garbage reads
            float4 xv = *(const float4*)(&xs[tc*LDX + 4*e4]);
            aK[i] += xv.x*wk.x + xv.y*wk.y + xv.z*wk.z + xv.w*wk.w;
            aV[i] += xv.x*wvv.x + xv.y*wvv.y + xv.z*wvv.z + xv.w*wvv.w;
          }
        }
        float c1k = c1[128+h*HD+d], c2k = c2[128+h*HD+d];
        float c1v = c1[256+h*HD+d], c2v = c2[256+h*HD+d];
#pragma unroll
        for (int i=0;i<13;++i){
          int t = tg + 16*i;
          if (t < NTOK){
            float m = s_m[t], r = s_r[t];
            Kb[t*32+d] = f2bf(r*aK[i] - r*m*c1k + c2k);
            Vb[t*32+d] = f2bf(r*aV[i] - r*m*c1v + c2v);
          }
        }
      }
      __syncthreads();

#pragma unroll
      for (int qt = 0; qt < 7; ++qt){
        const int t0 = qt*32;
        // ---- Q tile (fp32) ----
        {
          const int q = tid & 31, dg = tid >> 5;
          int t = t0 + q; int tc = (t < NTOK) ? t : (NTOK-1);        // clamp
          float m = s_m[tc], r = s_r[tc];
          const float* r0 = WF + (size_t)(h*HD + dg)*128;
          const float* r1 = r0 + 16*128;
          float a0=0.f, a1=0.f;
          for (int e4=0;e4<32;++e4){
            float4 xv = *(const float4*)(&xs[tc*LDX + 4*e4]);
            float4 w0 = *(const float4*)(r0 + 4*e4);
            float4 w1 = *(const float4*)(r1 + 4*e4);
            a0 += xv.x*w0.x + xv.y*w0.y + xv.z*w0.z + xv.w*w0.w;
            a1 += xv.x*w1.x + xv.y*w1.y + xv.z*w1.z + xv.w*w1.w;
          }
          int n0 = h*HD + dg, n1 = n0 + 16;
          Qt[q*33+dg]    = r*a0 - r*m*c1[n0] + c2[n0];
          Qt[q*33+dg+16] = r*a1 - r*m*c1[n1] + c2[n1];
        }
        __syncthreads();
        // ---- scores + row max (Kb rows via 16B LDS loads) ----
        {
          const int q = tid & 31, kg = tid >> 5;
          float qreg[32];
#pragma unroll
          for (int c=0;c<32;++c) qreg[c] = Qt[q*33+c];
          float pmax = -INFINITY;
          for (int j=0;j<13;++j){
            int k = kg + 16*j;
            if (k < NTOK){
              const u16x8* kr = (const u16x8*)(Kb + k*32);
              float s = 0.f;
#pragma unroll
              for (int v8=0;v8<4;++v8){
                u16x8 kv = kr[v8];
#pragma unroll
                for (int c=0;c<8;++c) s += qreg[v8*8+c]*bf2f(kv[c]);
              }
              pmax = fmaxf(pmax, s);
              Sb[q*204+k] = f2bf(s);
            }
          }
          pmax = fmaxf(pmax, __shfl_xor(pmax, 32));
          if (!(tid & 32)) red[(tid>>6)*33 + q] = pmax;
        }
        __syncthreads();
        if (tid < 32){
          float m = red[tid];
#pragma unroll
          for (int w=1;w<8;++w) m = fmaxf(m, red[w*33+tid]);
          mrow[tid] = m;
        }
        __syncthreads();
        // ---- exp + row sum ----
        {
          const int q = tid & 31, kg = tid >> 5;
          float mr = mrow[q];
          float psum = 0.f;
          for (int j=0;j<13;++j){
            int k = kg + 16*j;
            if (k < NTOK){
              float sv = bf2f(Sb[q*204+k]);
              float pe = __expf(sv - mr);
              psum += pe;
              Sb[q*204+k] = f2bf(pe);
            }
          }
          psum += __shfl_xor(psum, 32);
          if (!(tid & 32)) red[(tid>>6)*33 + q] = psum;
        }
        __syncthreads();
        if (tid < 32){
          float s = red[tid];
#pragma unroll
          for (int w=1;w<8;++w) s += red[w*33+tid];
          dsum[tid] = s;
        }
        __syncthreads();
        // ---- PV -> o tile (overwrite Qt); Sb via 8B loads, 4 k/iter ----
        {
          const int q = tid & 31, dg = tid >> 5;
          float o0=0.f, o1=0.f;
          const unsigned short* sp = Sb + q*204;
          for (int k4=0;k4<50;++k4){
            u16x4 sp4 = *(const u16x4*)(sp + 4*k4);
#pragma unroll
            for (int j=0;j<4;++j){
              int k = 4*k4+j;
              float pv = bf2f(sp4[j]);
              o0 += pv*bf2f(Vb[k*32+dg]);
              o1 += pv*bf2f(Vb[k*32+dg+16]);
            }
          }
          { // k = 200 tail
            float pv = bf2f(sp[200]);
            o0 += pv*bf2f(Vb[200*32+dg]);
            o1 += pv*bf2f(Vb[200*32+dg+16]);
          }
          float inv = 1.0f/dsum[q];
          Qt[q*33+dg]    = o0*inv;
          Qt[q*33+dg+16] = o1*inv;
        }
        __syncthreads();
        // ---- fold Wo into accA ----
        {
          const int trow = tid & 31, jb = tid >> 5;
          const float* wbase = WoT + (size_t)(h*HD)*128 + jb*8;
          for (int d=0;d<HD;++d){
            float ov = Qt[trow*33+d];
            float4 w0 = *(const float4*)(wbase + (size_t)d*128);
            float4 w1 = *(const float4*)(wbase + (size_t)d*128 + 4);
            accA[qt][0] += ov*w0.x; accA[qt][1] += ov*w0.y;
            accA[qt][2] += ov*w0.z; accA[qt][3] += ov*w0.w;
            accA[qt][4] += ov*w1.x; accA[qt][5] += ov*w1.y;
            accA[qt][6] += ov*w1.z; accA[qt][7] += ov*w1.w;
          }
        }
        __syncthreads();
      } // qt
    } // h

    // ---- apply attention delta + bo ----
    {
      const int trow = tid & 31, jb = tid >> 5;
      float4 b0 = *(const float4*)(bo + jb*8);
      float4 b1v = *(const float4*)(bo + jb*8 + 4);
      float bov[8] = {b0.x,b0.y,b0.z,b0.w,b1v.x,b1v.y,b1v.z,b1v.w};
#pragma unroll
      for (int qt=0;qt<7;++qt){
        int t = qt*32 + trow;
        if (t < NTOK){
          float* xr = &xs[t*LDX + jb*8];
#pragma unroll
          for (int jj=0;jj<8;++jj) xr[jj] += accA[qt][jj] + bov[jj];
        }
      }
    }
    __syncthreads();

    ln_stats(xs, s_m, s_r, tid);   // ln2 stats
    __syncthreads();

    // ---- gate (softmax over 5 experts) ----
    if (tid < NTOK){
      const float* row = xs + tid*LDX;
      float m = s_m[tid], r = s_r[tid];
      float gl[NEXP];
#pragma unroll
      for (int x=0;x<NEXP;++x) gl[x] = bg[x];
      for (int e=0;e<EDIM;++e){
        float hv = (row[e]-m)*r*ln2w[e] + ln2b[e];
#pragma unroll
        for (int x=0;x<NEXP;++x) gl[x] += hv*Wg[e*NEXP+x];
      }
      float gm = gl[0];
#pragma unroll
      for (int x=1;x<NEXP;++x) gm = fmaxf(gm, gl[x]);
      float gs = 0.f;
#pragma unroll
      for (int x=0;x<NEXP;++x){ gl[x] = __expf(gl[x]-gm); gs += gl[x]; }
      float gi = 1.0f/gs;
#pragma unroll
      for (int x=0;x<NEXP;++x) gateb[tid*NEXP+x] = gl[x]*gi;
    }
    __syncthreads();

    // ---- MoE: MFMA, 32-token tiles, gate folded into hid, acc across experts ----
    for (int t0 = 0; t0 < NTOK; t0 += 32){
      // A-stage: ln2(x) split hi/lo bf16, frag-packed (dest = tid*16B, linear)
      {
        int mf = tid >> 8;
        int row = (tid & 15) + 16*mf;
        int kb  = ((tid>>6)&3)*32 + 8*((tid>>4)&3);
        int t = t0 + row;
        union { unsigned short u[8]; bfrag v; } hu, lu;
        if (t < NTOK){
          float m = s_m[t], r = s_r[t];
          const float* xr = &xs[t*LDX + kb];
          float4 a = *(const float4*)xr;
          float4 bq = *(const float4*)(xr+4);
          float4 w0 = *(const float4*)(ln2w + kb);
          float4 w1 = *(const float4*)(ln2w + kb + 4);
          float4 bb0 = *(const float4*)(ln2b + kb);
          float4 bb1 = *(const float4*)(ln2b + kb + 4);
          float vv[8] = {(a.x-m)*r*w0.x+bb0.x, (a.y-m)*r*w0.y+bb0.y,
                         (a.z-m)*r*w0.z+bb0.z, (a.w-m)*r*w0.w+bb0.w,
                         (bq.x-m)*r*w1.x+bb1.x, (bq.y-m)*r*w1.y+bb1.y,
                         (bq.z-m)*r*w1.z+bb1.z, (bq.w-m)*r*w1.w+bb1.w};
#pragma unroll
          for (int j=0;j<8;++j){
            unsigned short hb = f2bf(vv[j]);
            hu.u[j] = hb;
            lu.u[j] = f2bf(vv[j] - bf2f(hb));
          }
        } else {
#pragma unroll
          for (int j=0;j<8;++j){ hu.u[j]=0; lu.u[j]=0; }
        }
        *(bfrag*)(Ahi + tid*8) = hu.v;
        *(bfrag*)(Alo + tid*8) = lu.v;
      }
      __syncthreads();

      f32x4 acc2[2];
      acc2[0] = (f32x4){0.f,0.f,0.f,0.f};
      acc2[1] = (f32x4){0.f,0.f,0.f,0.f};

      for (int x = 0; x < NEXP; ++x){
        const unsigned short* W1hx = p.W1h + (size_t)(li*NEXP+x)*FFD*EDIM;
        const unsigned short* W1lx = p.W1l + (size_t)(li*NEXP+x)*FFD*EDIM;
        const unsigned short* W2hx = p.W2h + (size_t)(li*NEXP+x)*EDIM*FFD;
        const unsigned short* W2lx = p.W2l + (size_t)(li*NEXP+x)*EDIM*FFD;

        // GEMM1: [32x128] @ [128x256] -> wave owns 32 n-cols
        f32x4 acc1[2][2];
#pragma unroll
        for (int i=0;i<2;++i){ acc1[i][0]=(f32x4){0,0,0,0}; acc1[i][1]=(f32x4){0,0,0,0}; }
#pragma unroll
        for (int kf=0;kf<4;++kf){
          bfrag ah[2], al[2], bh[2], bl[2];
#pragma unroll
          for (int mf=0;mf<2;++mf){
            ah[mf] = *(const bfrag*)(Ahi + ((mf*4+kf)*64 + lane)*8);
            al[mf] = *(const bfrag*)(Alo + ((mf*4+kf)*64 + lane)*8);
          }
#pragma unroll
          for (int nfl=0;nfl<2;++nfl){
            size_t n = (size_t)((wv*2+nfl)*16 + (lane&15));
            size_t off = n*128 + kf*32 + 8*(lane>>4);
            bh[nfl] = *(const bfrag*)(W1hx + off);
            bl[nfl] = *(const bfrag*)(W1lx + off);
          }
#pragma unroll
          for (int mf=0;mf<2;++mf)
#pragma unroll
            for (int nfl=0;nfl<2;++nfl){
              acc1[mf][nfl] = __builtin_amdgcn_mfma_f32_16x16x32_bf16(ah[mf], bh[nfl], acc1[mf][nfl], 0,0,0);
              acc1[mf][nfl] = __builtin_amdgcn_mfma_f32_16x16x32_bf16(ah[mf], bl[nfl], acc1[mf][nfl], 0,0,0);
              acc1[mf][nfl] = __builtin_amdgcn_mfma_f32_16x16x32_bf16(al[mf], bh[nfl], acc1[mf][nfl], 0,0,0);
            }
        }
        // epilogue: bias, relu, gate-scale, split, scatter to hid frag layout
        {
          int c = lane & 15;
#pragma unroll
          for (int nfl=0;nfl<2;++nfl){
            int n = (wv*2+nfl)*16 + c;
            float bb = b1g[x*FFD + n];
            int lane_t_base = 16*(2*nfl + (c>>3));
            int jcol = c & 7;
#pragma unroll
            for (int mf=0;mf<2;++mf){
#pragma unroll
              for (int reg=0;reg<4;++reg){
                int msub = (lane>>4)*4 + reg;
                int t = t0 + mf*16 + msub;
                float g = (t < NTOK) ? gateb[t*NEXP+x] : 0.f;
                float v = fmaxf(acc1[mf][nfl][reg] + bb, 0.f) * g;
                unsigned short hb = f2bf(v);
                unsigned short lb = f2bf(v - bf2f(hb));
                int idx = ((mf*8 + wv)*64 + msub + lane_t_base)*8 + jcol;
                Hh[idx] = hb; Hl[idx] = lb;
              }
            }
          }
        }
        __syncthreads();

        // GEMM2: [32x256] @ [256x128] -> wave owns 16 n-cols; acc across experts
#pragma unroll
        for (int kf=0;kf<8;++kf){
          bfrag hh[2], hl[2];
#pragma unroll
          for (int mf=0;mf<2;++mf){
            hh[mf] = *(const bfrag*)(Hh + ((mf*8+kf)*64 + lane)*8);
            hl[mf] = *(const bfrag*)(Hl + ((mf*8+kf)*64 + lane)*8);
          }
          size_t off = (size_t)(wv*16 + (lane&15))*256 + kf*32 + 8*(lane>>4);
          bfrag wh = *(const bfrag*)(W2hx + off);
          bfrag wl = *(const bfrag*)(W2lx + off);
#pragma unroll
          for (int mf=0;mf<2;++mf){
            acc2[mf] = __builtin_amdgcn_mfma_f32_16x16x32_bf16(hh[mf], wh, acc2[mf], 0,0,0);
            acc2[mf] = __builtin_amdgcn_mfma_f32_16x16x32_bf16(hh[mf], wl, acc2[mf], 0,0,0);
            acc2[mf] = __builtin_amdgcn_mfma_f32_16x16x32_bf16(hl[mf], wh, acc2[mf], 0,0,0);
          }
        }
        __syncthreads();   // hid free for next expert's epilogue
      } // x

      // tile epilogue: + sum_x g*b2, RMW xs
      {
        int c = lane & 15;
        int n = wv*16 + c;
#pragma unroll
        for (int mf=0;mf<2;++mf){
#pragma unroll
          for (int reg=0;reg<4;++reg){
            int t = t0 + mf*16 + (lane>>4)*4 + reg;
            if (t < NTOK){
              float bs = 0.f;
#pragma unroll
              for (int x=0;x<NEXP;++x) bs += gateb[t*NEXP+x]*b2g[x*EDIM+n];
              xs[t*LDX+n] += acc2[mf][reg] + bs;
            }
          }
        }
      }
      __syncthreads();     // Ahi/Alo reuse next tile
    } // tiles
  } // layers

  if (tid < EDIM) p.out[b*EDIM + tid] = xs[200*LDX + tid];
}

extern "C" void kernel_launch(void* const* d_in, const int* in_sizes, int n_in,
                              void* d_out, int out_size, void* d_ws, size_t ws_size,
                              hipStream_t stream) {
  (void)in_sizes; (void)n_in; (void)out_size; (void)ws_size;
  char* ws = (char*)d_ws;

  const float* Wqkv = (const float*)d_in[11];
  const float* bqkv = (const float*)d_in[12];
  const float* ln1w = (const float*)d_in[9];
  const float* ln1b = (const float*)d_in[10];
  const float* Wo   = (const float*)d_in[13];
  const float* W1   = (const float*)d_in[19];
  const float* W2   = (const float*)d_in[21];

  hipLaunchKernelGGL(prep_qkv, dim3(6*384), dim3(128), 0, stream,
                     Wqkv, bqkv, ln1w, ln1b,
                     (float*)(ws+OFF_WF), (float*)(ws+OFF_C1), (float*)(ws+OFF_C2));
  hipLaunchKernelGGL(prep_wo, dim3(384), dim3(256), 0, stream, Wo, (float*)(ws+OFF_WOT));
  hipLaunchKernelGGL(prep_moe, dim3(3840), dim3(256), 0, stream, W1, W2,
                     (unsigned short*)(ws+OFF_W1H), (unsigned short*)(ws+OFF_W1L),
                     (unsigned short*)(ws+OFF_W2H), (unsigned short*)(ws+OFF_W2L));

  Params p;
  p.x_cat        = (const int*)  d_in[0];
  p.x_num        = (const float*)d_in[1];
  p.x_eng        = (const float*)d_in[2];
  p.emb          = (const float*)d_in[3];
  p.emb_bias     = (const float*)d_in[4];
  p.emb_eng      = (const float*)d_in[5];
  p.emb_bias_eng = (const float*)d_in[6];
  p.ln0w = (const float*)d_in[7];  p.ln0b = (const float*)d_in[8];
  p.ln2w = (const float*)d_in[15]; p.ln2b = (const float*)d_in[16];
  p.bo   = (const float*)d_in[14];
  p.Wg   = (const float*)d_in[17]; p.bg = (const float*)d_in[18];
  p.b1   = (const float*)d_in[20]; p.b2 = (const float*)d_in[22];
  p.WF  = (const float*)(ws+OFF_WF);
  p.c1  = (const float*)(ws+OFF_C1);
  p.c2  = (const float*)(ws+OFF_C2);
  p.WoT = (const float*)(ws+OFF_WOT);
  p.W1h = (const unsigned short*)(ws+OFF_W1H);
  p.W1l = (const unsigned short*)(ws+OFF_W1L);
  p.W2h = (const unsigned short*)(ws+OFF_W2H);
  p.W2l = (const unsigned short*)(ws+OFF_W2L);
  p.out = (float*)d_out;

  hipLaunchKernelGGL(fam_fwd, dim3(NB), dim3(512), 0, stream, p);
}

// Round 5
// 5538.886 us; speedup vs baseline: 6.6503x; 2.0280x over previous
//
#include <hip/hip_runtime.h>
#include <math.h>

#define NTOK 201
#define EDIM 128
#define LDX  132
#define NHEAD 4
#define HD   32
#define NLAY 6
#define NEXP 5
#define FFD  256
#define NCAT 53
#define NNUM 47
#define NENG 100
#define NEMB 1352
#define SEQL 51
#define NB   512
#define LN_EPS 1e-5f
#define SCALE 0.17677669529663687f

typedef __attribute__((ext_vector_type(8))) short bfrag;           // 8 bf16
typedef __attribute__((ext_vector_type(4))) float f32x4;           // mfma acc
typedef __attribute__((ext_vector_type(8))) unsigned short u16x8;
typedef __attribute__((ext_vector_type(4))) unsigned short u16x4;

__device__ __forceinline__ float bf2f(unsigned short u){ return __uint_as_float(((unsigned)u)<<16); }
__device__ __forceinline__ unsigned short f2bf(float f){
  unsigned u = __float_as_uint(f);
  return (unsigned short)((u + 0x7FFFu + ((u>>16)&1u)) >> 16);
}

// ---------------- workspace layout (bytes) ----------------
#define OFF_WQH  0u            // Wqkv hi  [6][384][128] bf16 (Q rows pre-scaled)
#define OFF_WQL  589824u       // Wqkv lo
#define OFF_BQ   1179648u      // bqkv f32 [6][384] (Q rows pre-scaled)
#define OFF_WOH  1188864u      // Wo hi [6][128][128] bf16 (row-major [j][d])
#define OFF_WOL  1385472u      // Wo lo
#define OFF_W1H  1582080u      // W1T hi [6][5][256][128] bf16
#define OFF_W1L  3548160u
#define OFF_W2H  5514240u      // W2T hi [6][5][128][256] bf16
#define OFF_W2L  7480320u
// end 9446400

// ---------------- prep kernels ----------------
__global__ void prep_qkv_bf(const float* __restrict__ Wqkv, const float* __restrict__ bqkv,
                            unsigned short* __restrict__ Wqh, unsigned short* __restrict__ Wql,
                            float* __restrict__ bq){
  int bid = blockIdx.x; int n = bid % 384; int e = threadIdx.x;
  float sc = (n < 128) ? SCALE : 1.0f;
  float w = Wqkv[(size_t)bid*128 + e] * sc;
  unsigned short h = f2bf(w), l = f2bf(w - bf2f(h));
  Wqh[(size_t)bid*128 + e] = h; Wql[(size_t)bid*128 + e] = l;
  if (e == 0) bq[bid] = bqkv[bid] * sc;
}

__global__ void prep_wo_bf(const float* __restrict__ Wo,
                           unsigned short* __restrict__ Woh, unsigned short* __restrict__ Wol){
  int idx = blockIdx.x*blockDim.x + threadIdx.x;
  if (idx >= 6*128*128) return;
  float w = Wo[idx];
  unsigned short h = f2bf(w), l = f2bf(w - bf2f(h));
  Woh[idx] = h; Wol[idx] = l;
}

__global__ void prep_moe(const float* __restrict__ W1, const float* __restrict__ W2,
                         unsigned short* __restrict__ W1h, unsigned short* __restrict__ W1l,
                         unsigned short* __restrict__ W2h, unsigned short* __restrict__ W2l){
  const int Ntot = 6*5*128*256;
  for (int idx = blockIdx.x*blockDim.x + threadIdx.x; idx < Ntot; idx += gridDim.x*blockDim.x){
    int lx = idx / 32768; int rem = idx & 32767; int e = rem >> 8; int f = rem & 255;
    float w = W1[idx];
    unsigned short h = f2bf(w); unsigned short l = f2bf(w - bf2f(h));
    size_t o1 = (size_t)(lx*256+f)*128 + e;
    W1h[o1] = h; W1l[o1] = l;
    int f2 = (idx >> 7) & 255; int e2 = idx & 127;
    float w2 = W2[idx];
    unsigned short h2 = f2bf(w2); unsigned short l2 = f2bf(w2 - bf2f(h2));
    size_t o2 = (size_t)(lx*128+e2)*256 + f2;
    W2h[o2] = h2; W2l[o2] = l2;
  }
}

// ---------------- main kernel ----------------
struct Params {
  const int*   x_cat;
  const float* x_num;
  const float* x_eng;
  const float* emb;
  const float* emb_bias;
  const float* emb_eng;
  const float* emb_bias_eng;
  const float* ln0w; const float* ln0b;
  const float* ln1w; const float* ln1b;
  const float* ln2w; const float* ln2b;
  const float* bo;
  const float* Wg;   const float* bg;
  const float* b1;   const float* b2;
  const unsigned short* Wqh; const unsigned short* Wql; const float* bq;
  const unsigned short* Woh; const unsigned short* Wol;
  const unsigned short* W1h; const unsigned short* W1l;
  const unsigned short* W2h; const unsigned short* W2l;
  float* out;
};

__device__ __forceinline__ void ln_stats(const float* xs, float* s_m, float* s_r, int tid){
  if (tid < NTOK){
    const float* row = xs + tid*LDX;
    float s0=0,s1=0,s2=0,s3=0;
    for (int e=0;e<EDIM;e+=4){ s0+=row[e]; s1+=row[e+1]; s2+=row[e+2]; s3+=row[e+3]; }
    float m = (s0+s1+s2+s3)*(1.0f/EDIM);
    float v0=0,v1=0,v2=0,v3=0;
    for (int e=0;e<EDIM;e+=4){
      float d0=row[e]-m,d1=row[e+1]-m,d2=row[e+2]-m,d3=row[e+3]-m;
      v0+=d0*d0; v1+=d1*d1; v2+=d2*d2; v3+=d3*d3;
    }
    s_m[tid]=m; s_r[tid]=1.0f/sqrtf((v0+v1+v2+v3)*(1.0f/EDIM)+LN_EPS);
  }
}

__global__ __launch_bounds__(512) __attribute__((amdgpu_waves_per_eu(2,2)))
void fam_fwd(Params p){
  __shared__ float xs[NTOK*LDX];          // 106,128 B
  __shared__ float s_m[NTOK], s_r[NTOK];  // 1,608 B
  __shared__ __align__(16) char scb[55296];

  const int b = blockIdx.x, tid = threadIdx.x;
  const int lane = tid & 63, wv = tid >> 6;

  // ---- Phase 0: embeddings ----
  {
    const int e = tid & 127, tl = tid >> 7;
    for (int t = tl; t < NTOK; t += 4){
      float v;
      if (t < NCAT){
        int idx = p.x_cat[b*(SEQL*NCAT) + (SEQL-1)*NCAT + t];
        v = p.emb[idx*EDIM+e] + p.emb_bias[t*EDIM+e];
      } else if (t < NCAT+NNUM){
        int j = t - NCAT;
        float nv = p.x_num[b*(SEQL*NNUM)+(SEQL-1)*NNUM+j];
        v = p.emb[(NEMB-NNUM+1+j)*EDIM+e]*nv + p.emb_bias[(NCAT+j)*EDIM+e];
      } else if (t < NCAT+NNUM+NENG){
        int j = t - (NCAT+NNUM);
        float ev = p.x_eng[b*NENG+j];
        v = p.emb_eng[j*EDIM+e]*ev + p.emb_bias_eng[j*EDIM+e];
      } else v = 0.f;
      xs[t*LDX+e] = v;
    }
  }
  __syncthreads();
  ln_stats(xs, s_m, s_r, tid);
  __syncthreads();
  {
    const int e = tid & 127, tl = tid >> 7;
    for (int t = tl; t < NTOK; t += 4){
      float m = s_m[t], r = s_r[t];
      xs[t*LDX+e] = (xs[t*LDX+e]-m)*r*p.ln0w[e] + p.ln0b[e];
    }
  }
  __syncthreads();

  // ---- attn LDS pointers ----
  unsigned short* Kh  = (unsigned short*)scb;                    // [224][40]
  unsigned short* Vt  = (unsigned short*)(scb + 17920);          // [32][232]
  unsigned short* HTh = (unsigned short*)(scb + 32768);          // [32][136]
  unsigned short* HTl = (unsigned short*)(scb + 32768 + 8704);   // [32][136]
  unsigned short* Sb  = (unsigned short*)(scb + 32768);          // [32][232] (aliases HT)
  unsigned short* Ob  = (unsigned short*)(scb + 32768 + 14848);  // [32][40]
  unsigned short* Qmh = (unsigned short*)(scb + 50176);          // [32][40]
  unsigned short* Qml = (unsigned short*)(scb + 52736);          // [32][40]
  float* red  = (float*)(scb + 52736);                           // [8][33] (aliases Qml)
  float* mrow = (float*)(scb + 52736 + 1056);                    // [32]
  float* dsum = (float*)(scb + 52736 + 1184);                    // [32]
  // ---- moe LDS pointers ----
  unsigned short* Ahi = (unsigned short*)scb;
  unsigned short* Alo = (unsigned short*)(scb + 8192);
  unsigned short* Hh  = (unsigned short*)(scb + 16384);
  unsigned short* Hl  = (unsigned short*)(scb + 32768);
  float*          gateb = (float*)(scb + 49152);

  for (int li = 0; li < NLAY; ++li){
    const float* ln1w = p.ln1w + li*EDIM;
    const float* ln1b = p.ln1b + li*EDIM;
    const float* ln2w = p.ln2w + li*EDIM;
    const float* ln2b = p.ln2b + li*EDIM;
    const float* bo   = p.bo + li*EDIM;
    const float* Wg   = p.Wg + li*EDIM*NEXP;
    const float* bg   = p.bg + li*NEXP;
    const float* b1g  = p.b1 + li*NEXP*FFD;
    const float* b2g  = p.b2 + li*NEXP*EDIM;

    ln_stats(xs, s_m, s_r, tid);   // ln1
    __syncthreads();

    f32x4 accW[7][2];              // Wo-folded attention delta, per-wave C-frags
#pragma unroll
    for (int mt=0; mt<7; ++mt){ accW[mt][0]=(f32x4){0,0,0,0}; accW[mt][1]=(f32x4){0,0,0,0}; }

    const int mfw = wv & 1;        // wave m-frag
    const int ngw = wv >> 1;       // wave n-group

    for (int h = 0; h < NHEAD; ++h){
      // ======== pass 1: K and V for all tokens ========
      {
        // wave: mf = mfw; sel = ngw: 0/1 -> K nf, 2/3 -> V nf
        int sel = ngw;
        int nrow = ((sel < 2) ? (128 + h*HD + sel*16) : (256 + h*HD + (sel-2)*16)) + (lane & 15);
        const unsigned short* Bh = p.Wqh + ((size_t)li*384 + nrow)*128 + 8*(lane>>4);
        const unsigned short* Bl = p.Wql + ((size_t)li*384 + nrow)*128 + 8*(lane>>4);
        bfrag wbh[4], wbl[4];
#pragma unroll
        for (int kf=0; kf<4; ++kf){ wbh[kf] = *(const bfrag*)(Bh + kf*32); wbl[kf] = *(const bfrag*)(Bl + kf*32); }
        float bias = p.bq[li*384 + nrow];

        for (int mt=0; mt<7; ++mt){
          // stage HT hi/lo (ln1 applied)
          {
            int row = tid >> 4, c8 = (tid & 15) << 3;
            int t = mt*32 + row;
            union { unsigned short u[8]; u16x8 v; } hu, lu;
            if (t < NTOK){
              float m = s_m[t], r = s_r[t];
              const float* xr = &xs[t*LDX + c8];
              float4 a = *(const float4*)xr, b4 = *(const float4*)(xr+4);
              float4 w0 = *(const float4*)(ln1w + c8), w1 = *(const float4*)(ln1w + c8 + 4);
              float4 q0 = *(const float4*)(ln1b + c8), q1 = *(const float4*)(ln1b + c8 + 4);
              float vv[8] = {(a.x-m)*r*w0.x+q0.x,(a.y-m)*r*w0.y+q0.y,(a.z-m)*r*w0.z+q0.z,(a.w-m)*r*w0.w+q0.w,
                             (b4.x-m)*r*w1.x+q1.x,(b4.y-m)*r*w1.y+q1.y,(b4.z-m)*r*w1.z+q1.z,(b4.w-m)*r*w1.w+q1.w};
#pragma unroll
              for (int j2=0;j2<8;++j2){ unsigned short hb=f2bf(vv[j2]); hu.u[j2]=hb; lu.u[j2]=f2bf(vv[j2]-bf2f(hb)); }
            } else {
#pragma unroll
              for (int j2=0;j2<8;++j2){ hu.u[j2]=0; lu.u[j2]=0; }
            }
            *(u16x8*)(HTh + row*136 + c8) = hu.v;
            *(u16x8*)(HTl + row*136 + c8) = lu.v;
          }
          __syncthreads();
          // GEMM + epilogue
          {
            f32x4 acc = (f32x4){0,0,0,0};
#pragma unroll
            for (int kf=0; kf<4; ++kf){
              const unsigned short* ab = HTh + (mfw*16 + (lane&15))*136 + kf*32 + 8*(lane>>4);
              const unsigned short* al = HTl + (mfw*16 + (lane&15))*136 + kf*32 + 8*(lane>>4);
              bfrag ah = *(const bfrag*)ab, av = *(const bfrag*)al;
              acc = __builtin_amdgcn_mfma_f32_16x16x32_bf16(ah, wbh[kf], acc, 0,0,0);
              acc = __builtin_amdgcn_mfma_f32_16x16x32_bf16(ah, wbl[kf], acc, 0,0,0);
              acc = __builtin_amdgcn_mfma_f32_16x16x32_bf16(av, wbh[kf], acc, 0,0,0);
            }
            int col = lane & 15;
            if (sel < 2){
              int d = sel*16 + col;
#pragma unroll
              for (int reg=0; reg<4; ++reg){
                int tok = mt*32 + mfw*16 + 4*(lane>>4) + reg;
                Kh[tok*40 + d] = f2bf(acc[reg] + bias);
              }
            } else {
              int d = (sel-2)*16 + col;
              int tokb = mt*32 + mfw*16 + 4*(lane>>4);
              u16x4 pk;
#pragma unroll
              for (int reg=0; reg<4; ++reg) pk[reg] = f2bf(acc[reg] + bias);
              *(u16x4*)(Vt + d*232 + tokb) = pk;
            }
          }
          __syncthreads();
        }
      }

      // ======== pass 2: per q-tile attention ========
      // hoist Wo B-frags: wave (mfw, ngw): n-frags {ngw, ngw+4}
      bfrag wobh[2], wobl[2];
#pragma unroll
      for (int i=0;i<2;++i){
        int j = (ngw + 4*i)*16 + (lane&15);
        const unsigned short* wb = p.Woh + ((size_t)li*128 + j)*128 + h*HD + 8*(lane>>4);
        const unsigned short* wl = p.Wol + ((size_t)li*128 + j)*128 + h*HD + 8*(lane>>4);
        wobh[i] = *(const bfrag*)wb; wobl[i] = *(const bfrag*)wl;
      }

#pragma unroll
      for (int mt=0; mt<7; ++mt){
        // stage HT
        {
          int row = tid >> 4, c8 = (tid & 15) << 3;
          int t = mt*32 + row;
          union { unsigned short u[8]; u16x8 v; } hu, lu;
          if (t < NTOK){
            float m = s_m[t], r = s_r[t];
            const float* xr = &xs[t*LDX + c8];
            float4 a = *(const float4*)xr, b4 = *(const float4*)(xr+4);
            float4 w0 = *(const float4*)(ln1w + c8), w1 = *(const float4*)(ln1w + c8 + 4);
            float4 q0 = *(const float4*)(ln1b + c8), q1 = *(const float4*)(ln1b + c8 + 4);
            float vv[8] = {(a.x-m)*r*w0.x+q0.x,(a.y-m)*r*w0.y+q0.y,(a.z-m)*r*w0.z+q0.z,(a.w-m)*r*w0.w+q0.w,
                           (b4.x-m)*r*w1.x+q1.x,(b4.y-m)*r*w1.y+q1.y,(b4.z-m)*r*w1.z+q1.z,(b4.w-m)*r*w1.w+q1.w};
#pragma unroll
            for (int j2=0;j2<8;++j2){ unsigned short hb=f2bf(vv[j2]); hu.u[j2]=hb; lu.u[j2]=f2bf(vv[j2]-bf2f(hb)); }
          } else {
#pragma unroll
            for (int j2=0;j2<8;++j2){ hu.u[j2]=0; lu.u[j2]=0; }
          }
          *(u16x8*)(HTh + row*136 + c8) = hu.v;
          *(u16x8*)(HTl + row*136 + c8) = lu.v;
        }
        __syncthreads();

        // Q-GEMM (waves 0-3): mf2 = wv&1, nf = (wv>>1)&1
        if (wv < 4){
          int mf2 = wv & 1, nf = (wv >> 1) & 1;
          int nrow = h*HD + nf*16 + (lane & 15);
          const unsigned short* Bh = p.Wqh + ((size_t)li*384 + nrow)*128 + 8*(lane>>4);
          const unsigned short* Bl = p.Wql + ((size_t)li*384 + nrow)*128 + 8*(lane>>4);
          f32x4 acc = (f32x4){0,0,0,0};
#pragma unroll
          for (int kf=0; kf<4; ++kf){
            bfrag ah = *(const bfrag*)(HTh + (mf2*16 + (lane&15))*136 + kf*32 + 8*(lane>>4));
            bfrag av = *(const bfrag*)(HTl + (mf2*16 + (lane&15))*136 + kf*32 + 8*(lane>>4));
            bfrag bh = *(const bfrag*)(Bh + kf*32);
            bfrag bl = *(const bfrag*)(Bl + kf*32);
            acc = __builtin_amdgcn_mfma_f32_16x16x32_bf16(ah, bh, acc, 0,0,0);
            acc = __builtin_amdgcn_mfma_f32_16x16x32_bf16(ah, bl, acc, 0,0,0);
            acc = __builtin_amdgcn_mfma_f32_16x16x32_bf16(av, bh, acc, 0,0,0);
          }
          float bias = p.bq[li*384 + nrow];
          int d = nf*16 + (lane & 15);
#pragma unroll
          for (int reg=0; reg<4; ++reg){
            float v = acc[reg] + bias;
            unsigned short hb = f2bf(v);
            int qrow = mf2*16 + 4*(lane>>4) + reg;
            Qmh[qrow*40 + d] = hb;
            Qml[qrow*40 + d] = f2bf(v - bf2f(hb));
          }
        }
        __syncthreads();

        // scores: S = Qh@K^T + Ql@K^T -> Sb bf16
        {
          bfrag qh = *(const bfrag*)(Qmh + (mfw*16 + (lane&15))*40 + 8*(lane>>4));
          bfrag ql = *(const bfrag*)(Qml + (mfw*16 + (lane&15))*40 + 8*(lane>>4));
          for (int nf = ngw; nf < 14; nf += 4){
            bfrag kb = *(const bfrag*)(Kh + (nf*16 + (lane&15))*40 + 8*(lane>>4));
            f32x4 s = (f32x4){0,0,0,0};
            s = __builtin_amdgcn_mfma_f32_16x16x32_bf16(qh, kb, s, 0,0,0);
            s = __builtin_amdgcn_mfma_f32_16x16x32_bf16(ql, kb, s, 0,0,0);
            int tok = nf*16 + (lane & 15);
#pragma unroll
            for (int reg=0; reg<4; ++reg){
              int q = mfw*16 + 4*(lane>>4) + reg;
              Sb[q*232 + tok] = f2bf(s[reg]);
            }
          }
        }
        __syncthreads();

        // row max
        {
          int q = tid & 31, kg = tid >> 5;
          float pmax = -INFINITY;
#pragma unroll
          for (int j2=0; j2<14; ++j2){
            int k = kg + 16*j2;
            if (k < NTOK) pmax = fmaxf(pmax, bf2f(Sb[q*232 + k]));
          }
          pmax = fmaxf(pmax, __shfl_xor(pmax, 32));
          if (!(tid & 32)) red[(tid>>6)*33 + q] = pmax;
        }
        __syncthreads();
        if (tid < 32){
          float m = red[tid];
#pragma unroll
          for (int w=1; w<8; ++w) m = fmaxf(m, red[w*33 + tid]);
          mrow[tid] = m;
        }
        __syncthreads();

        // exp + row sum (zero pad cols >= 201)
        {
          int q = tid & 31, kg = tid >> 5;
          float mr = mrow[q];
          float psum = 0.f;
#pragma unroll
          for (int j2=0; j2<14; ++j2){
            int k = kg + 16*j2;
            float pe = 0.f;
            if (k < NTOK) pe = __expf(bf2f(Sb[q*232 + k]) - mr);
            psum += pe;
            Sb[q*232 + k] = f2bf(pe);
          }
          psum += __shfl_xor(psum, 32);
          if (!(tid & 32)) red[(tid>>6)*33 + q] = psum;
        }
        __syncthreads();
        if (tid < 32){
          float s = red[tid];
#pragma unroll
          for (int w=1; w<8; ++w) s += red[w*33 + tid];
          dsum[tid] = s;
        }
        __syncthreads();

        // PV (waves 0-3): O = P @ V
        if (wv < 4){
          int mf2 = wv & 1, nf = (wv >> 1) & 1;
          f32x4 o = (f32x4){0,0,0,0};
#pragma unroll
          for (int kf=0; kf<7; ++kf){
            bfrag pa = *(const bfrag*)(Sb + (mf2*16 + (lane&15))*232 + kf*32 + 8*(lane>>4));
            bfrag vb = *(const bfrag*)(Vt + (nf*16 + (lane&15))*232 + kf*32 + 8*(lane>>4));
            o = __builtin_amdgcn_mfma_f32_16x16x32_bf16(pa, vb, o, 0,0,0);
          }
          int d = nf*16 + (lane & 15);
#pragma unroll
          for (int reg=0; reg<4; ++reg){
            int q = mf2*16 + 4*(lane>>4) + reg;
            Ob[q*40 + d] = f2bf(o[reg] * (1.0f/dsum[q]));
          }
        }
        __syncthreads();

        // Wo fold into accW[mt]
        {
          bfrag oa = *(const bfrag*)(Ob + (mfw*16 + (lane&15))*40 + 8*(lane>>4));
          accW[mt][0] = __builtin_amdgcn_mfma_f32_16x16x32_bf16(oa, wobh[0], accW[mt][0], 0,0,0);
          accW[mt][0] = __builtin_amdgcn_mfma_f32_16x16x32_bf16(oa, wobl[0], accW[mt][0], 0,0,0);
          accW[mt][1] = __builtin_amdgcn_mfma_f32_16x16x32_bf16(oa, wobh[1], accW[mt][1], 0,0,0);
          accW[mt][1] = __builtin_amdgcn_mfma_f32_16x16x32_bf16(oa, wobl[1], accW[mt][1], 0,0,0);
        }
        __syncthreads();
      } // mt
    } // h

    // ---- apply attention delta + bo ----
    {
#pragma unroll
      for (int i=0;i<2;++i){
        int j = (ngw + 4*i)*16 + (lane & 15);
        float boj = bo[j];
#pragma unroll
        for (int mt=0; mt<7; ++mt){
#pragma unroll
          for (int reg=0; reg<4; ++reg){
            int t = mt*32 + mfw*16 + 4*(lane>>4) + reg;
            if (t < NTOK) xs[t*LDX + j] += accW[mt][i][reg] + boj;
          }
        }
      }
    }
    __syncthreads();

    ln_stats(xs, s_m, s_r, tid);   // ln2
    __syncthreads();

    // ---- gate ----
    if (tid < NTOK){
      const float* row = xs + tid*LDX;
      float m = s_m[tid], r = s_r[tid];
      float gl[NEXP];
#pragma unroll
      for (int x=0;x<NEXP;++x) gl[x] = bg[x];
      for (int e=0;e<EDIM;++e){
        float hv = (row[e]-m)*r*ln2w[e] + ln2b[e];
#pragma unroll
        for (int x=0;x<NEXP;++x) gl[x] += hv*Wg[e*NEXP+x];
      }
      float gm = gl[0];
#pragma unroll
      for (int x=1;x<NEXP;++x) gm = fmaxf(gm, gl[x]);
      float gs = 0.f;
#pragma unroll
      for (int x=0;x<NEXP;++x){ gl[x] = __expf(gl[x]-gm); gs += gl[x]; }
      float gi = 1.0f/gs;
#pragma unroll
      for (int x=0;x<NEXP;++x) gateb[tid*NEXP+x] = gl[x]*gi;
    }
    __syncthreads();

    // ---- MoE: MFMA, 32-token tiles ----
    for (int t0 = 0; t0 < NTOK; t0 += 32){
      {
        int mf = tid >> 8;
        int row = (tid & 15) + 16*mf;
        int kb  = ((tid>>6)&3)*32 + 8*((tid>>4)&3);
        int t = t0 + row;
        union { unsigned short u[8]; bfrag v; } hu, lu;
        if (t < NTOK){
          float m = s_m[t], r = s_r[t];
          const float* xr = &xs[t*LDX + kb];
          float4 a = *(const float4*)xr;
          float4 bq4 = *(const float4*)(xr+4);
          float4 w0 = *(const float4*)(ln2w + kb);
          float4 w1 = *(const float4*)(ln2w + kb + 4);
          float4 bb0 = *(const float4*)(ln2b + kb);
          float4 bb1 = *(const float4*)(ln2b + kb + 4);
          float vv[8] = {(a.x-m)*r*w0.x+bb0.x, (a.y-m)*r*w0.y+bb0.y,
                         (a.z-m)*r*w0.z+bb0.z, (a.w-m)*r*w0.w+bb0.w,
                         (bq4.x-m)*r*w1.x+bb1.x, (bq4.y-m)*r*w1.y+bb1.y,
                         (bq4.z-m)*r*w1.z+bb1.z, (bq4.w-m)*r*w1.w+bb1.w};
#pragma unroll
          for (int j=0;j<8;++j){
            unsigned short hb = f2bf(vv[j]);
            hu.u[j] = hb;
            lu.u[j] = f2bf(vv[j] - bf2f(hb));
          }
        } else {
#pragma unroll
          for (int j=0;j<8;++j){ hu.u[j]=0; lu.u[j]=0; }
        }
        *(bfrag*)(Ahi + tid*8) = hu.v;
        *(bfrag*)(Alo + tid*8) = lu.v;
      }
      __syncthreads();

      f32x4 acc2[2];
      acc2[0] = (f32x4){0.f,0.f,0.f,0.f};
      acc2[1] = (f32x4){0.f,0.f,0.f,0.f};

      for (int x = 0; x < NEXP; ++x){
        const unsigned short* W1hx = p.W1h + (size_t)(li*NEXP+x)*FFD*EDIM;
        const unsigned short* W1lx = p.W1l + (size_t)(li*NEXP+x)*FFD*EDIM;
        const unsigned short* W2hx = p.W2h + (size_t)(li*NEXP+x)*EDIM*FFD;
        const unsigned short* W2lx = p.W2l + (size_t)(li*NEXP+x)*EDIM*FFD;

        f32x4 acc1[2][2];
#pragma unroll
        for (int i=0;i<2;++i){ acc1[i][0]=(f32x4){0,0,0,0}; acc1[i][1]=(f32x4){0,0,0,0}; }
#pragma unroll
        for (int kf=0;kf<4;++kf){
          bfrag ah[2], al[2], bh[2], bl[2];
#pragma unroll
          for (int mf=0;mf<2;++mf){
            ah[mf] = *(const bfrag*)(Ahi + ((mf*4+kf)*64 + lane)*8);
            al[mf] = *(const bfrag*)(Alo + ((mf*4+kf)*64 + lane)*8);
          }
#pragma unroll
          for (int nfl=0;nfl<2;++nfl){
            size_t n = (size_t)((wv*2+nfl)*16 + (lane&15));
            size_t off = n*128 + kf*32 + 8*(lane>>4);
            bh[nfl] = *(const bfrag*)(W1hx + off);
            bl[nfl] = *(const bfrag*)(W1lx + off);
          }
#pragma unroll
          for (int mf=0;mf<2;++mf)
#pragma unroll
            for (int nfl=0;nfl<2;++nfl){
              acc1[mf][nfl] = __builtin_amdgcn_mfma_f32_16x16x32_bf16(ah[mf], bh[nfl], acc1[mf][nfl], 0,0,0);
              acc1[mf][nfl] = __builtin_amdgcn_mfma_f32_16x16x32_bf16(ah[mf], bl[nfl], acc1[mf][nfl], 0,0,0);
              acc1[mf][nfl] = __builtin_amdgcn_mfma_f32_16x16x32_bf16(al[mf], bh[nfl], acc1[mf][nfl], 0,0,0);
            }
        }
        {
          int c = lane & 15;
#pragma unroll
          for (int nfl=0;nfl<2;++nfl){
            int n = (wv*2+nfl)*16 + c;
            float bb = b1g[x*FFD + n];
            int lane_t_base = 16*(2*nfl + (c>>3));
            int jcol = c & 7;
#pragma unroll
            for (int mf=0;mf<2;++mf){
#pragma unroll
              for (int reg=0;reg<4;++reg){
                int msub = (lane>>4)*4 + reg;
                int t = t0 + mf*16 + msub;
                float g = (t < NTOK) ? gateb[t*NEXP+x] : 0.f;
                float v = fmaxf(acc1[mf][nfl][reg] + bb, 0.f) * g;
                unsigned short hb = f2bf(v);
                unsigned short lb = f2bf(v - bf2f(hb));
                int idx = ((mf*8 + wv)*64 + msub + lane_t_base)*8 + jcol;
                Hh[idx] = hb; Hl[idx] = lb;
              }
            }
          }
        }
        __syncthreads();

#pragma unroll
        for (int kf=0;kf<8;++kf){
          bfrag hh[2], hl[2];
#pragma unroll
          for (int mf=0;mf<2;++mf){
            hh[mf] = *(const bfrag*)(Hh + ((mf*8+kf)*64 + lane)*8);
            hl[mf] = *(const bfrag*)(Hl + ((mf*8+kf)*64 + lane)*8);
          }
          size_t off = (size_t)(wv*16 + (lane&15))*256 + kf*32 + 8*(lane>>4);
          bfrag wh = *(const bfrag*)(W2hx + off);
          bfrag wl = *(const bfrag*)(W2lx + off);
#pragma unroll
          for (int mf=0;mf<2;++mf){
            acc2[mf] = __builtin_amdgcn_mfma_f32_16x16x32_bf16(hh[mf], wh, acc2[mf], 0,0,0);
            acc2[mf] = __builtin_amdgcn_mfma_f32_16x16x32_bf16(hh[mf], wl, acc2[mf], 0,0,0);
            acc2[mf] = __builtin_amdgcn_mfma_f32_16x16x32_bf16(hl[mf], wh, acc2[mf], 0,0,0);
          }
        }
        __syncthreads();
      } // x

      {
        int c = lane & 15;
        int n = wv*16 + c;
#pragma unroll
        for (int mf=0;mf<2;++mf){
#pragma unroll
          for (int reg=0;reg<4;++reg){
            int t = t0 + mf*16 + (lane>>4)*4 + reg;
            if (t < NTOK){
              float bs = 0.f;
#pragma unroll
              for (int x=0;x<NEXP;++x) bs += gateb[t*NEXP+x]*b2g[x*EDIM+n];
              xs[t*LDX+n] += acc2[mf][reg] + bs;
            }
          }
        }
      }
      __syncthreads();
    } // tiles
  } // layers

  if (tid < EDIM) p.out[b*EDIM + tid] = xs[200*LDX + tid];
}

extern "C" void kernel_launch(void* const* d_in, const int* in_sizes, int n_in,
                              void* d_out, int out_size, void* d_ws, size_t ws_size,
                              hipStream_t stream) {
  (void)in_sizes; (void)n_in; (void)out_size; (void)ws_size;
  char* ws = (char*)d_ws;

  const float* Wqkv = (const float*)d_in[11];
  const float* bqkv = (const float*)d_in[12];
  const float* Wo   = (const float*)d_in[13];
  const float* W1   = (const float*)d_in[19];
  const float* W2   = (const float*)d_in[21];

  hipLaunchKernelGGL(prep_qkv_bf, dim3(6*384), dim3(128), 0, stream,
                     Wqkv, bqkv,
                     (unsigned short*)(ws+OFF_WQH), (unsigned short*)(ws+OFF_WQL),
                     (float*)(ws+OFF_BQ));
  hipLaunchKernelGGL(prep_wo_bf, dim3(384), dim3(256), 0, stream, Wo,
                     (unsigned short*)(ws+OFF_WOH), (unsigned short*)(ws+OFF_WOL));
  hipLaunchKernelGGL(prep_moe, dim3(3840), dim3(256), 0, stream, W1, W2,
                     (unsigned short*)(ws+OFF_W1H), (unsigned short*)(ws+OFF_W1L),
                     (unsigned short*)(ws+OFF_W2H), (unsigned short*)(ws+OFF_W2L));

  Params p;
  p.x_cat        = (const int*)  d_in[0];
  p.x_num        = (const float*)d_in[1];
  p.x_eng        = (const float*)d_in[2];
  p.emb          = (const float*)d_in[3];
  p.emb_bias     = (const float*)d_in[4];
  p.emb_eng      = (const float*)d_in[5];
  p.emb_bias_eng = (const float*)d_in[6];
  p.ln0w = (const float*)d_in[7];  p.ln0b = (const float*)d_in[8];
  p.ln1w = (const float*)d_in[9];  p.ln1b = (const float*)d_in[10];
  p.ln2w = (const float*)d_in[15]; p.ln2b = (const float*)d_in[16];
  p.bo   = (const float*)d_in[14];
  p.Wg   = (const float*)d_in[17]; p.bg = (const float*)d_in[18];
  p.b1   = (const float*)d_in[20]; p.b2 = (const float*)d_in[22];
  p.Wqh = (const unsigned short*)(ws+OFF_WQH);
  p.Wql = (const unsigned short*)(ws+OFF_WQL);
  p.bq  = (const float*)(ws+OFF_BQ);
  p.Woh = (const unsigned short*)(ws+OFF_WOH);
  p.Wol = (const unsigned short*)(ws+OFF_WOL);
  p.W1h = (const unsigned short*)(ws+OFF_W1H);
  p.W1l = (const unsigned short*)(ws+OFF_W1L);
  p.W2h = (const unsigned short*)(ws+OFF_W2H);
  p.W2l = (const unsigned short*)(ws+OFF_W2L);
  p.out = (float*)d_out;

  hipLaunchKernelGGL(fam_fwd, dim3(NB), dim3(512), 0, stream, p);
}